// Round 2
// baseline (7064.351 us; speedup 1.0000x reference)
//
#include <hip/hip_runtime.h>
#include <cstddef>

// ---------------------------------------------------------------------------
// ChebNet: B=32, N=1024, cheb layers (6->128->512->1024, K=3), maxpool, 3 FCs.
// Batch-chunked (4 x 8 samples) to keep workspace ~72 MB.
// A stored bf16; Laplacian fused into L*X; proj fused (3 terms+bias+relu);
// layer-3 maxpool fused via atomicMax.
// ---------------------------------------------------------------------------

#define NN 1024
#define BC 8
#define NCHUNK 4

__device__ inline unsigned short f2bf(float f) {
    unsigned int u = __float_as_uint(f);
    u = (u + 0x7fffu + ((u >> 16) & 1u)) >> 16;
    return (unsigned short)u;
}
__device__ inline float bf2f(unsigned short s) {
    return __uint_as_float(((unsigned int)s) << 16);
}

__global__ void zero_kernel(float* __restrict__ p, int n) {
    int i = blockIdx.x * blockDim.x + threadIdx.x;
    if (i < n) p[i] = 0.f;
}

// sq[row] = sum_d X[row,d]^2   (rows = BC*NN)
__global__ void rowsq_kernel(const float* __restrict__ X, float* __restrict__ sq, int F) {
    int row = blockIdx.x * blockDim.x + threadIdx.x;
    if (row >= BC * NN) return;
    const float* p = X + (size_t)row * F;
    float s = 0.f;
    for (int d = 0; d < F; ++d) s += p[d] * p[d];
    sq[row] = s;
}

// A[b,n,m] = exp(2 x_n.x_m - sq_n - sq_m) -> bf16; deg[b,n] += rowsum (fp32)
__global__ __launch_bounds__(256) void adj_kernel(
    const float* __restrict__ X, const float* __restrict__ sq,
    unsigned short* __restrict__ Abf, float* __restrict__ deg, int F) {
    int b = blockIdx.z;
    int n0 = blockIdx.y * 64, m0 = blockIdx.x * 64;
    const float* Xb = X + (size_t)b * NN * F;
    unsigned short* Ab = Abf + (size_t)b * NN * NN;
    const float* sqb = sq + b * NN;
    float* degb = deg + b * NN;

    __shared__ float As[16][68];
    __shared__ float Bs[16][68];
    int t = threadIdx.x, tx = t & 15, ty = t >> 4;
    float acc[4][4] = {};

    for (int k0 = 0; k0 < F; k0 += 16) {
        if ((F & 15) == 0) {
            int i = t >> 2, q = t & 3;
            float4 av = *(const float4*)(&Xb[(size_t)(n0 + i) * F + k0 + q * 4]);
            float4 bv = *(const float4*)(&Xb[(size_t)(m0 + i) * F + k0 + q * 4]);
            As[q * 4 + 0][i] = av.x; As[q * 4 + 1][i] = av.y;
            As[q * 4 + 2][i] = av.z; As[q * 4 + 3][i] = av.w;
            Bs[q * 4 + 0][i] = bv.x; Bs[q * 4 + 1][i] = bv.y;
            Bs[q * 4 + 2][i] = bv.z; Bs[q * 4 + 3][i] = bv.w;
        } else {
            for (int e = t; e < 64 * 16; e += 256) {
                int i = e >> 4, kk = e & 15, kg = k0 + kk;
                float av = 0.f, bv = 0.f;
                if (kg < F) { av = Xb[(size_t)(n0 + i) * F + kg]; bv = Xb[(size_t)(m0 + i) * F + kg]; }
                As[kk][i] = av; Bs[kk][i] = bv;
            }
        }
        __syncthreads();
#pragma unroll
        for (int kk = 0; kk < 16; ++kk) {
            float4 a4 = *(const float4*)(&As[kk][ty * 4]);
            float4 b4 = *(const float4*)(&Bs[kk][tx * 4]);
            float aa[4] = {a4.x, a4.y, a4.z, a4.w};
            float bb[4] = {b4.x, b4.y, b4.z, b4.w};
#pragma unroll
            for (int u = 0; u < 4; ++u)
#pragma unroll
                for (int v = 0; v < 4; ++v) acc[u][v] += aa[u] * bb[v];
        }
        __syncthreads();
    }

    float rs[4];
#pragma unroll
    for (int u = 0; u < 4; ++u) {
        int n = n0 + ty * 4 + u;
        float sn = sqb[n];
        float e0 = __expf(2.f * acc[u][0] - sn - sqb[m0 + tx * 4 + 0]);
        float e1 = __expf(2.f * acc[u][1] - sn - sqb[m0 + tx * 4 + 1]);
        float e2 = __expf(2.f * acc[u][2] - sn - sqb[m0 + tx * 4 + 2]);
        float e3 = __expf(2.f * acc[u][3] - sn - sqb[m0 + tx * 4 + 3]);
        rs[u] = e0 + e1 + e2 + e3;
        ushort4 pk;
        pk.x = f2bf(e0); pk.y = f2bf(e1); pk.z = f2bf(e2); pk.w = f2bf(e3);
        *(ushort4*)(&Ab[(size_t)n * NN + m0 + tx * 4]) = pk;
    }
    // reduce rs over the 16 tx lanes (contiguous within a wave)
#pragma unroll
    for (int off = 8; off > 0; off >>= 1) {
#pragma unroll
        for (int u = 0; u < 4; ++u) rs[u] += __shfl_down(rs[u], off);
    }
    if (tx == 0) {
#pragma unroll
        for (int u = 0; u < 4; ++u) atomicAdd(&degb[n0 + ty * 4 + u], rs[u]);
    }
}

__global__ void dis_kernel(const float* __restrict__ deg, float* __restrict__ dis) {
    int i = blockIdx.x * blockDim.x + threadIdx.x;
    if (i < BC * NN) dis[i] = rsqrtf(deg[i]);
}

// Out = L*Xin (mode 0) or 2*L*Xin - Xprev (mode 1), L = I - Dn A Dm fused.
__global__ __launch_bounds__(256) void lx_kernel(
    const unsigned short* __restrict__ Abf, const float* __restrict__ dis,
    const float* __restrict__ Xin, float* __restrict__ Out,
    const float* __restrict__ Xprev, int F, int mode) {
    int b = blockIdx.z;
    int n0 = blockIdx.y * 64, f0 = blockIdx.x * 64;
    const unsigned short* Ab = Abf + (size_t)b * NN * NN;
    const float* db = dis + b * NN;
    const float* Xb = Xin + (size_t)b * NN * F;

    __shared__ float As[16][68];
    __shared__ float Bs[16][68];
    int t = threadIdx.x, tx = t & 15, ty = t >> 4;
    float acc[4][4] = {};

    for (int k0 = 0; k0 < NN; k0 += 16) {
        {
            int i = t >> 2, q = t & 3;
            ushort4 a4 = *(const ushort4*)(&Ab[(size_t)(n0 + i) * NN + k0 + q * 4]);
            As[q * 4 + 0][i] = bf2f(a4.x); As[q * 4 + 1][i] = bf2f(a4.y);
            As[q * 4 + 2][i] = bf2f(a4.z); As[q * 4 + 3][i] = bf2f(a4.w);
        }
        for (int e = t; e < 16 * 64; e += 256) {
            int kk = e >> 6, j = e & 63, f = f0 + j;
            Bs[kk][j] = (f < F) ? db[k0 + kk] * Xb[(size_t)(k0 + kk) * F + f] : 0.f;
        }
        __syncthreads();
#pragma unroll
        for (int kk = 0; kk < 16; ++kk) {
            float4 a4 = *(const float4*)(&As[kk][ty * 4]);
            float4 b4 = *(const float4*)(&Bs[kk][tx * 4]);
            float aa[4] = {a4.x, a4.y, a4.z, a4.w};
            float bb[4] = {b4.x, b4.y, b4.z, b4.w};
#pragma unroll
            for (int u = 0; u < 4; ++u)
#pragma unroll
                for (int v = 0; v < 4; ++v) acc[u][v] += aa[u] * bb[v];
        }
        __syncthreads();
    }
#pragma unroll
    for (int u = 0; u < 4; ++u) {
        int n = n0 + ty * 4 + u;
        float dn = db[n];
#pragma unroll
        for (int v = 0; v < 4; ++v) {
            int f = f0 + tx * 4 + v;
            if (f < F) {
                size_t idx = ((size_t)b * NN + n) * F + f;
                float c = Xb[(size_t)n * F + f] - dn * acc[u][v];
                if (mode) c = 2.f * c - Xprev[idx];
                Out[idx] = c;
            }
        }
    }
}

// Out[r,g] = relu(sum_p Xp[r,:] Wp[:,g] + bias[g]); if Out==nullptr, maxpool
// over rows into pool[(b0+row0/N)*1024+g] via atomicMax (values >= 0).
__global__ __launch_bounds__(256) void proj_kernel(
    const float* __restrict__ X0, const float* __restrict__ X1, const float* __restrict__ X2,
    const float* __restrict__ W, const float* __restrict__ bias,
    float* __restrict__ Out, float* __restrict__ pool, int Fi, int Fo, int b0) {
    int row0 = blockIdx.y * 64, g0 = blockIdx.x * 64;

    __shared__ float As[16][68];
    __shared__ float Bs[16][68];
    int t = threadIdx.x, tx = t & 15, ty = t >> 4;
    float acc[4][4] = {};
    const float* Xs[3] = {X0, X1, X2};

    for (int p = 0; p < 3; ++p) {
        const float* Ap = Xs[p];
        const float* Wp = W + (size_t)p * Fi * Fo;
        for (int k0 = 0; k0 < Fi; k0 += 16) {
            for (int e = t; e < 64 * 16; e += 256) {
                int i = e >> 4, kk = e & 15, kg = k0 + kk;
                As[kk][i] = (kg < Fi) ? Ap[(size_t)(row0 + i) * Fi + kg] : 0.f;
            }
            for (int e = t; e < 16 * 64; e += 256) {
                int kk = e >> 6, j = e & 63, kg = k0 + kk;
                Bs[kk][j] = (kg < Fi) ? Wp[(size_t)kg * Fo + g0 + j] : 0.f;
            }
            __syncthreads();
#pragma unroll
            for (int kk = 0; kk < 16; ++kk) {
                float4 a4 = *(const float4*)(&As[kk][ty * 4]);
                float4 b4 = *(const float4*)(&Bs[kk][tx * 4]);
                float aa[4] = {a4.x, a4.y, a4.z, a4.w};
                float bb[4] = {b4.x, b4.y, b4.z, b4.w};
#pragma unroll
                for (int u = 0; u < 4; ++u)
#pragma unroll
                    for (int v = 0; v < 4; ++v) acc[u][v] += aa[u] * bb[v];
            }
            __syncthreads();
        }
    }

    if (Out) {
#pragma unroll
        for (int u = 0; u < 4; ++u) {
            int r = row0 + ty * 4 + u;
#pragma unroll
            for (int v = 0; v < 4; ++v) {
                int g = g0 + tx * 4 + v;
                float c = fmaxf(acc[u][v] + bias[g], 0.f);
                Out[(size_t)r * Fo + g] = c;
            }
        }
    } else {
        float ml[4];
#pragma unroll
        for (int v = 0; v < 4; ++v) {
            int g = g0 + tx * 4 + v;
            float m = 0.f;
#pragma unroll
            for (int u = 0; u < 4; ++u) m = fmaxf(m, fmaxf(acc[u][v] + bias[g], 0.f));
            ml[v] = m;
        }
#pragma unroll
        for (int v = 0; v < 4; ++v) As[ty][tx * 4 + v] = ml[v];
        __syncthreads();
        if (t < 64) {
            float m = As[0][t];
#pragma unroll
            for (int y = 1; y < 16; ++y) m = fmaxf(m, As[y][t]);
            int pb = b0 + (row0 >> 10);
            atomicMax((int*)&pool[(size_t)pb * 1024 + g0 + t], __float_as_int(m));
        }
    }
}

// out[32,Nout] = relu?(In[32,K] @ W[K,Nout] + b)
__global__ void fc_kernel(const float* __restrict__ In, const float* __restrict__ W,
                          const float* __restrict__ bias, float* __restrict__ out,
                          int K, int Nout, int relu) {
    int idx = blockIdx.x * blockDim.x + threadIdx.x;
    if (idx >= 32 * Nout) return;
    int r = idx / Nout, c = idx % Nout;
    float s = bias[c];
    const float* ip = In + (size_t)r * K;
    for (int k = 0; k < K; ++k) s += ip[k] * W[(size_t)k * Nout + c];
    if (relu) s = fmaxf(s, 0.f);
    out[idx] = s;
}

// ---------------------------------------------------------------------------
extern "C" void kernel_launch(void* const* d_in, const int* in_sizes, int n_in,
                              void* d_out, int out_size, void* d_ws, size_t ws_size,
                              hipStream_t stream) {
    const float* x    = (const float*)d_in[0];
    const float* W1   = (const float*)d_in[1];
    const float* b1   = (const float*)d_in[2];
    const float* W2   = (const float*)d_in[3];
    const float* b2   = (const float*)d_in[4];
    const float* W3   = (const float*)d_in[5];
    const float* b3   = (const float*)d_in[6];
    const float* fc1w = (const float*)d_in[7];
    const float* fc1b = (const float*)d_in[8];
    const float* fc2w = (const float*)d_in[9];
    const float* fc2b = (const float*)d_in[10];
    const float* fc3w = (const float*)d_in[11];
    const float* fc3b = (const float*)d_in[12];
    float* out = (float*)d_out;

    float* ws = (float*)d_ws;
    unsigned short* Abf = (unsigned short*)ws;   // BC*N*N bf16 = 16 MiB (4M floats)
    float* X1c  = ws + 4194304;                  // BC*N*512 max = 16 MiB
    float* X2c  = X1c + 4194304;                 // 16 MiB
    float* O1c  = X2c + 4194304;                 // BC*N*128 = 4 MiB
    float* O2c  = O1c + 1048576;                 // BC*N*512 = 16 MiB
    float* sq   = O2c + 4194304;                 // 8192
    float* deg  = sq + 8192;                     // 8192
    float* dis  = deg + 8192;                    // 8192
    float* pool = dis + 8192;                    // 32*1024
    float* f1   = pool + 32768;                  // 32*512
    float* f2   = f1 + 16384;                    // 32*128
    // total ~17.9M floats ~ 72 MB

    zero_kernel<<<128, 256, 0, stream>>>(pool, 32768);

    for (int c = 0; c < NCHUNK; ++c) {
        int b0 = c * BC;
        struct LayerDef { const float* Xin; int Fi; const float* W; const float* bias; int Fo; float* Out; };
        LayerDef L[3] = {
            { x + (size_t)b0 * NN * 6, 6,   W1, b1, 128,  O1c },
            { O1c,                     128, W2, b2, 512,  O2c },
            { O2c,                     512, W3, b3, 1024, nullptr },  // fused maxpool
        };
        for (int li = 0; li < 3; ++li) {
            LayerDef& Ld = L[li];
            rowsq_kernel<<<32, 256, 0, stream>>>(Ld.Xin, sq, Ld.Fi);
            zero_kernel<<<32, 256, 0, stream>>>(deg, BC * NN);
            adj_kernel<<<dim3(16, 16, BC), 256, 0, stream>>>(Ld.Xin, sq, Abf, deg, Ld.Fi);
            dis_kernel<<<32, 256, 0, stream>>>(deg, dis);
            int ft = (Ld.Fi + 63) / 64;
            lx_kernel<<<dim3(ft, 16, BC), 256, 0, stream>>>(Abf, dis, Ld.Xin, X1c, nullptr, Ld.Fi, 0);
            lx_kernel<<<dim3(ft, 16, BC), 256, 0, stream>>>(Abf, dis, X1c, X2c, Ld.Xin, Ld.Fi, 1);
            proj_kernel<<<dim3(Ld.Fo / 64, BC * NN / 64), 256, 0, stream>>>(
                Ld.Xin, X1c, X2c, Ld.W, Ld.bias, Ld.Out, pool, Ld.Fi, Ld.Fo, b0);
        }
    }

    fc_kernel<<<(32 * 512 + 255) / 256, 256, 0, stream>>>(pool, fc1w, fc1b, f1, 1024, 512, 1);
    fc_kernel<<<(32 * 128 + 255) / 256, 256, 0, stream>>>(f1, fc2w, fc2b, f2, 512, 128, 1);
    fc_kernel<<<(32 * 40 + 255) / 256, 256, 0, stream>>>(f2, fc3w, fc3b, out, 128, 40, 0);
}

// Round 3
// 2445.260 us; speedup vs baseline: 2.8890x; 2.8890x over previous
//
#include <hip/hip_runtime.h>
#include <cstddef>

// ---------------------------------------------------------------------------
// ChebNet on MFMA bf16: B=32, N=1024, layers 6->128->512->1024 (K_cheb=3),
// maxpool, FC 1024->512->128->40.  Batch-chunked 4 x 8 samples (~84 MB ws).
// - adjacency: split-bf16 (hi+lo) MFMA NT-GEMM + exp epilogue -> A bf16
// - L*X: MFMA using A's symmetry (both operands k-contiguous), Laplacian fused
// - proj: MFMA over 3 stacked K segments, bias+relu fused; layer-3 maxpool fused
// ---------------------------------------------------------------------------

#define NN 1024
#define BC 8
#define NCHUNK 4

typedef unsigned short ushort_t;
typedef __bf16 bf16x8 __attribute__((ext_vector_type(8)));
typedef float f32x4 __attribute__((ext_vector_type(4)));

__device__ inline ushort_t f2bf(float f) {
    unsigned int u = __float_as_uint(f);
    u = (u + 0x7fffu + ((u >> 16) & 1u)) >> 16;
    return (ushort_t)u;
}
__device__ inline float bf2f(ushort_t s) {
    return __uint_as_float(((unsigned int)s) << 16);
}

__global__ void zero_kernel(float* __restrict__ p, int n) {
    int i = blockIdx.x * blockDim.x + threadIdx.x;
    if (i < n) p[i] = 0.f;
}

// W[p][Fi][Fo] fp32 -> Wt[p][Fo][Ks] bf16 (transposed, K zero-padded to Ks)
__global__ void wconv_kernel(const float* __restrict__ W, ushort_t* __restrict__ Wt,
                             int Fi, int Fo, int Ks, int total) {
    int idx = blockIdx.x * blockDim.x + threadIdx.x;
    if (idx >= total) return;
    int kk = idx % Ks;
    int rest = idx / Ks;
    int g = rest % Fo;
    int p = rest / Fo;
    float v = (kk < Fi) ? W[((size_t)p * Fi + kk) * Fo + g] : 0.f;
    Wt[idx] = f2bf(v);
}

// per row: hi/lo bf16 split (padded to Fp with zeros) + squared norm
__global__ __launch_bounds__(256) void prep_kernel(
    const float* __restrict__ X, ushort_t* __restrict__ hi, ushort_t* __restrict__ lo,
    float* __restrict__ sq, int F, int Fp) {
    int t = threadIdx.x;
    int row = blockIdx.x * 4 + (t >> 6);
    int lane = t & 63;
    const float* Xr = X + (size_t)row * F;
    float s = 0.f;
    for (int f = lane; f < Fp; f += 64) {
        float x = (f < F) ? Xr[f] : 0.f;
        ushort_t h = f2bf(x);
        float l = x - bf2f(h);
        hi[(size_t)row * Fp + f] = h;
        lo[(size_t)row * Fp + f] = f2bf(l);
        s += x * x;
    }
#pragma unroll
    for (int off = 32; off > 0; off >>= 1) s += __shfl_down(s, off);
    if (lane == 0) sq[row] = s;
}

// A[b,n,m] = exp(2*x_n.x_m - sq_n - sq_m) -> bf16, split-precision MFMA
__global__ __launch_bounds__(256) void adj_kernel(
    const ushort_t* __restrict__ hi, const ushort_t* __restrict__ lo,
    const float* __restrict__ sq, ushort_t* __restrict__ Abf, int Fp) {
    int t = threadIdx.x;
    int m0 = blockIdx.x * 128, n0 = blockIdx.y * 128, b = blockIdx.z;
    const ushort_t* Hb = hi + (size_t)b * NN * Fp;
    const ushort_t* Lb = lo + (size_t)b * NN * Fp;
    ushort_t* Ab = Abf + (size_t)b * NN * NN;
    const float* sqb = sq + (size_t)b * NN;

    int lane = t & 63, quad = lane >> 4, l16 = lane & 15, wave = t >> 6;
    int rowoff = (wave >> 1) * 64, coloff = (wave & 1) * 64;

    __shared__ __align__(16) ushort_t Ah[128][40];
    __shared__ __align__(16) ushort_t Al[128][40];
    __shared__ __align__(16) ushort_t Bh[128][40];
    __shared__ __align__(16) ushort_t Bl[128][40];

    f32x4 acc[4][4];
#pragma unroll
    for (int i = 0; i < 4; ++i)
#pragma unroll
        for (int j = 0; j < 4; ++j) acc[i][j] = (f32x4){0.f, 0.f, 0.f, 0.f};

    for (int k0 = 0; k0 < Fp; k0 += 32) {
        for (int s = t; s < 512; s += 256) {
            int rr = s >> 2, kq = (s & 3) * 8;
            *(uint4*)&Ah[rr][kq] = *(const uint4*)(Hb + (size_t)(n0 + rr) * Fp + k0 + kq);
            *(uint4*)&Al[rr][kq] = *(const uint4*)(Lb + (size_t)(n0 + rr) * Fp + k0 + kq);
            *(uint4*)&Bh[rr][kq] = *(const uint4*)(Hb + (size_t)(m0 + rr) * Fp + k0 + kq);
            *(uint4*)&Bl[rr][kq] = *(const uint4*)(Lb + (size_t)(m0 + rr) * Fp + k0 + kq);
        }
        __syncthreads();
        bf16x8 ah[4], al[4], bh[4], bl[4];
#pragma unroll
        for (int i = 0; i < 4; ++i) {
            ah[i] = *(const bf16x8*)&Ah[rowoff + i * 16 + l16][quad * 8];
            al[i] = *(const bf16x8*)&Al[rowoff + i * 16 + l16][quad * 8];
        }
#pragma unroll
        for (int j = 0; j < 4; ++j) {
            bh[j] = *(const bf16x8*)&Bh[coloff + j * 16 + l16][quad * 8];
            bl[j] = *(const bf16x8*)&Bl[coloff + j * 16 + l16][quad * 8];
        }
#pragma unroll
        for (int i = 0; i < 4; ++i)
#pragma unroll
            for (int j = 0; j < 4; ++j) {
                acc[i][j] = __builtin_amdgcn_mfma_f32_16x16x32_bf16(al[i], bh[j], acc[i][j], 0, 0, 0);
                acc[i][j] = __builtin_amdgcn_mfma_f32_16x16x32_bf16(ah[i], bl[j], acc[i][j], 0, 0, 0);
                acc[i][j] = __builtin_amdgcn_mfma_f32_16x16x32_bf16(ah[i], bh[j], acc[i][j], 0, 0, 0);
            }
        __syncthreads();
    }
#pragma unroll
    for (int j = 0; j < 4; ++j) {
        int m = m0 + coloff + j * 16 + l16;
        float sm = sqb[m];
#pragma unroll
        for (int i = 0; i < 4; ++i) {
#pragma unroll
            for (int r = 0; r < 4; ++r) {
                int n = n0 + rowoff + i * 16 + quad * 4 + r;
                float v = __expf(2.f * acc[i][j][r] - sqb[n] - sm);
                Ab[(size_t)n * NN + m] = f2bf(v);
            }
        }
    }
}

// dis[row] = rsqrt(rowsum(A[row,:]))
__global__ __launch_bounds__(256) void degdis_kernel(const ushort_t* __restrict__ Abf,
                                                     float* __restrict__ dis) {
    int t = threadIdx.x;
    int row = blockIdx.x * 4 + (t >> 6);
    int lane = t & 63;
    const ushort_t* Ar = Abf + (size_t)row * NN + lane * 16;
    uint4 v1 = *(const uint4*)Ar;
    uint4 v2 = *(const uint4*)(Ar + 8);
    float s = 0.f;
    const unsigned int* w1 = (const unsigned int*)&v1;
    const unsigned int* w2 = (const unsigned int*)&v2;
#pragma unroll
    for (int i = 0; i < 4; ++i) {
        s += bf2f((ushort_t)(w1[i] & 0xffff)) + bf2f((ushort_t)(w1[i] >> 16));
        s += bf2f((ushort_t)(w2[i] & 0xffff)) + bf2f((ushort_t)(w2[i] >> 16));
    }
#pragma unroll
    for (int off = 32; off > 0; off >>= 1) s += __shfl_down(s, off);
    if (lane == 0) dis[row] = rsqrtf(s);
}

// X fp32 [b*N+n][F] -> Xst bf16 [b][f][n] scaled by dis[n]
__global__ __launch_bounds__(256) void scaleT_kernel(
    const float* __restrict__ X, const float* __restrict__ dis,
    ushort_t* __restrict__ Xst, int F, int Fp) {
    int t = threadIdx.x;
    int n0 = blockIdx.x * 64, f0 = blockIdx.y * 64, b = blockIdx.z;
    __shared__ float T[64][65];
    const float* Xb = X + (size_t)(b * NN + n0) * F;
#pragma unroll
    for (int p = 0; p < 16; ++p) {
        int nr = (t >> 6) + 4 * p;
        int f = f0 + (t & 63);
        T[nr][t & 63] = (f < F) ? Xb[(size_t)nr * F + f] : 0.f;
    }
    __syncthreads();
    float dl = dis[(size_t)b * NN + n0 + (t & 63)];
#pragma unroll
    for (int p = 0; p < 16; ++p) {
        int fr = (t >> 6) + 4 * p;
        int f = f0 + fr;
        if (f < F)
            Xst[((size_t)b * Fp + f) * NN + n0 + (t & 63)] = f2bf(T[t & 63][fr] * dl);
    }
}

// transposed st [b][f][n] -> row-major [b*N+n][Fp] (zero pad f>=F), optional /dis[n]
__global__ __launch_bounds__(256) void trT_kernel(
    const ushort_t* __restrict__ src, const float* __restrict__ dis,
    ushort_t* __restrict__ dst, int F, int Fp, int inv) {
    int t = threadIdx.x;
    int n0 = blockIdx.x * 64, f0 = blockIdx.y * 64, b = blockIdx.z;
    __shared__ ushort_t T[64][66];
#pragma unroll
    for (int p = 0; p < 16; ++p) {
        int fr = (t >> 6) + 4 * p;
        int f = f0 + fr;
        ushort_t v = 0;
        if (f < F) v = src[((size_t)b * Fp + f) * NN + n0 + (t & 63)];
        T[fr][t & 63] = v;
    }
    __syncthreads();
    int f = f0 + (t & 63);
    if (f >= Fp) return;
#pragma unroll
    for (int p = 0; p < 16; ++p) {
        int nr = (t >> 6) + 4 * p;
        int n = n0 + nr;
        float sc = inv ? (1.f / dis[(size_t)b * NN + n]) : 1.f;
        float val = (f < F) ? bf2f(T[t & 63][nr]) * sc : 0.f;
        dst[((size_t)b * NN + n) * Fp + f] = f2bf(val);
    }
}

// transposed-space L*X: acc[f][n] = sum_k in_st[f][k]*A[k][n]  (A symmetric)
// mode0: out = X0st - dn^2*acc      ( = dn*X1t, i.e. next scaled operand)
// mode1: out = (2*X1st - X0st)/dn - 2*dn*acc  ( = X2t )
__global__ __launch_bounds__(256) void lx_kernel(
    const ushort_t* __restrict__ Abf, const float* __restrict__ dis,
    const ushort_t* __restrict__ in_st, const ushort_t* __restrict__ aux_st,
    ushort_t* __restrict__ out_st, int F, int Fp, int mode) {
    int t = threadIdx.x;
    int m0 = blockIdx.x * 128, n0 = blockIdx.y * 128, b = blockIdx.z;
    const ushort_t* Ain = in_st + (size_t)b * Fp * NN;
    const ushort_t* Ab = Abf + (size_t)b * NN * NN;

    int lane = t & 63, quad = lane >> 4, l16 = lane & 15, wave = t >> 6;
    int rowoff = (wave >> 1) * 64, coloff = (wave & 1) * 64;

    __shared__ __align__(16) ushort_t As[128][40];
    __shared__ __align__(16) ushort_t Bs[128][40];
    f32x4 acc[4][4];
#pragma unroll
    for (int i = 0; i < 4; ++i)
#pragma unroll
        for (int j = 0; j < 4; ++j) acc[i][j] = (f32x4){0.f, 0.f, 0.f, 0.f};

    for (int k0 = 0; k0 < NN; k0 += 32) {
        for (int s = t; s < 512; s += 256) {
            int rr = s >> 2, kq = (s & 3) * 8;
            uint4 v = make_uint4(0u, 0u, 0u, 0u);
            if (m0 + rr < F) v = *(const uint4*)(Ain + (size_t)(m0 + rr) * NN + k0 + kq);
            *(uint4*)&As[rr][kq] = v;
            *(uint4*)&Bs[rr][kq] = *(const uint4*)(Ab + (size_t)(n0 + rr) * NN + k0 + kq);
        }
        __syncthreads();
        bf16x8 af[4], bf[4];
#pragma unroll
        for (int i = 0; i < 4; ++i) af[i] = *(const bf16x8*)&As[rowoff + i * 16 + l16][quad * 8];
#pragma unroll
        for (int j = 0; j < 4; ++j) bf[j] = *(const bf16x8*)&Bs[coloff + j * 16 + l16][quad * 8];
#pragma unroll
        for (int i = 0; i < 4; ++i)
#pragma unroll
            for (int j = 0; j < 4; ++j)
                acc[i][j] = __builtin_amdgcn_mfma_f32_16x16x32_bf16(af[i], bf[j], acc[i][j], 0, 0, 0);
        __syncthreads();
    }
#pragma unroll
    for (int j = 0; j < 4; ++j) {
        int n = n0 + coloff + j * 16 + l16;
        float dn = dis[(size_t)b * NN + n];
        float inv = mode ? (1.f / dn) : 0.f;
        float dn2 = dn * dn;
#pragma unroll
        for (int i = 0; i < 4; ++i) {
#pragma unroll
            for (int r = 0; r < 4; ++r) {
                int f = m0 + rowoff + i * 16 + quad * 4 + r;
                if (f < F) {
                    size_t off = ((size_t)b * Fp + f) * NN + n;
                    float a = acc[i][j][r];
                    float xin = bf2f(in_st[off]);
                    float o;
                    if (mode == 0) {
                        o = xin - dn2 * a;
                    } else {
                        float x0 = bf2f(aux_st[off]);
                        o = inv * (2.f * xin - x0) - 2.f * dn * a;
                    }
                    out_st[off] = f2bf(o);
                }
            }
        }
    }
}

// Out[r][g] = relu( sum_p Xp[r][:]*Wt[p][g][:] + bias[g] ); layer3: fused maxpool
__global__ __launch_bounds__(256) void proj_kernel(
    const ushort_t* __restrict__ X0, const ushort_t* __restrict__ X1,
    const ushort_t* __restrict__ X2, const ushort_t* __restrict__ Wt,
    const float* __restrict__ bias, float* __restrict__ O, float* __restrict__ pool,
    int Fp, int Fo, int b0) {
    int t = threadIdx.x;
    int g0 = blockIdx.x * 128, r0 = blockIdx.y * 128;
    int lane = t & 63, quad = lane >> 4, l16 = lane & 15, wave = t >> 6;
    int rowoff = (wave >> 1) * 64, coloff = (wave & 1) * 64;

    __shared__ __align__(16) ushort_t As[128][40];
    __shared__ __align__(16) ushort_t Bs[128][40];
    f32x4 acc[4][4];
#pragma unroll
    for (int i = 0; i < 4; ++i)
#pragma unroll
        for (int j = 0; j < 4; ++j) acc[i][j] = (f32x4){0.f, 0.f, 0.f, 0.f};

    const ushort_t* Xs[3] = {X0, X1, X2};
    for (int p = 0; p < 3; ++p) {
        const ushort_t* Xp = Xs[p];
        const ushort_t* Wp = Wt + (size_t)p * Fo * Fp;
        for (int k0 = 0; k0 < Fp; k0 += 32) {
            for (int s = t; s < 512; s += 256) {
                int rr = s >> 2, kq = (s & 3) * 8;
                *(uint4*)&As[rr][kq] = *(const uint4*)(Xp + (size_t)(r0 + rr) * Fp + k0 + kq);
                *(uint4*)&Bs[rr][kq] = *(const uint4*)(Wp + (size_t)(g0 + rr) * Fp + k0 + kq);
            }
            __syncthreads();
            bf16x8 af[4], bf[4];
#pragma unroll
            for (int i = 0; i < 4; ++i) af[i] = *(const bf16x8*)&As[rowoff + i * 16 + l16][quad * 8];
#pragma unroll
            for (int j = 0; j < 4; ++j) bf[j] = *(const bf16x8*)&Bs[coloff + j * 16 + l16][quad * 8];
#pragma unroll
            for (int i = 0; i < 4; ++i)
#pragma unroll
                for (int j = 0; j < 4; ++j)
                    acc[i][j] = __builtin_amdgcn_mfma_f32_16x16x32_bf16(af[i], bf[j], acc[i][j], 0, 0, 0);
            __syncthreads();
        }
    }

    float bias_l[4];
#pragma unroll
    for (int j = 0; j < 4; ++j) bias_l[j] = bias[g0 + coloff + j * 16 + l16];

    if (O) {
#pragma unroll
        for (int i = 0; i < 4; ++i) {
#pragma unroll
            for (int r = 0; r < 4; ++r) {
                int row = r0 + rowoff + i * 16 + quad * 4 + r;
#pragma unroll
                for (int j = 0; j < 4; ++j) {
                    int g = g0 + coloff + j * 16 + l16;
                    O[(size_t)row * Fo + g] = fmaxf(acc[i][j][r] + bias_l[j], 0.f);
                }
            }
        }
    } else {
        float mj[4];
#pragma unroll
        for (int j = 0; j < 4; ++j) {
            float m = 0.f;
#pragma unroll
            for (int i = 0; i < 4; ++i)
#pragma unroll
                for (int r = 0; r < 4; ++r)
                    m = fmaxf(m, acc[i][j][r] + bias_l[j]);
            m = fmaxf(m, 0.f);
            m = fmaxf(m, __shfl_xor(m, 16));
            m = fmaxf(m, __shfl_xor(m, 32));
            mj[j] = m;
        }
        if (quad == 0) {
            int smp = b0 + (r0 >> 10);
#pragma unroll
            for (int j = 0; j < 4; ++j)
                atomicMax((int*)&pool[(size_t)smp * 1024 + g0 + coloff + j * 16 + l16],
                          __float_as_int(mj[j]));
        }
    }
}

__global__ void fc_kernel(const float* __restrict__ In, const float* __restrict__ W,
                          const float* __restrict__ bias, float* __restrict__ out,
                          int K, int Nout, int relu) {
    int idx = blockIdx.x * blockDim.x + threadIdx.x;
    if (idx >= 32 * Nout) return;
    int r = idx / Nout, c = idx % Nout;
    float s = bias[c];
    const float* ip = In + (size_t)r * K;
    for (int k = 0; k < K; ++k) s += ip[k] * W[(size_t)k * Nout + c];
    if (relu) s = fmaxf(s, 0.f);
    out[idx] = s;
}

// ---------------------------------------------------------------------------
extern "C" void kernel_launch(void* const* d_in, const int* in_sizes, int n_in,
                              void* d_out, int out_size, void* d_ws, size_t ws_size,
                              hipStream_t stream) {
    const float* x    = (const float*)d_in[0];
    const float* W1   = (const float*)d_in[1];
    const float* b1   = (const float*)d_in[2];
    const float* W2   = (const float*)d_in[3];
    const float* b2   = (const float*)d_in[4];
    const float* W3   = (const float*)d_in[5];
    const float* b3   = (const float*)d_in[6];
    const float* fc1w = (const float*)d_in[7];
    const float* fc1b = (const float*)d_in[8];
    const float* fc2w = (const float*)d_in[9];
    const float* fc2b = (const float*)d_in[10];
    const float* fc3w = (const float*)d_in[11];
    const float* fc3b = (const float*)d_in[12];
    float* out = (float*)d_out;

    ushort_t* Abf  = (ushort_t*)d_ws;            // 8M elems (16 MiB)
    ushort_t* X0hi = Abf + (size_t)8 * 1024 * 1024;
    ushort_t* X0lo = X0hi + 4194304;             // aliases X1st (disjoint lifetime)
    ushort_t* X0st = X0lo + 4194304;             // aliases X2b  (disjoint lifetime)
    ushort_t* X2bt = X0st + 4194304;
    ushort_t* X1b  = X2bt + 4194304;
    ushort_t* Wt   = X1b + 4194304;              // 1781760 elems
    float* O1   = (float*)(Wt + 1781760);        // 8192*128
    float* O2   = O1 + 1048576;                  // 8192*512
    float* sq   = O2 + 4194304;                  // 8192
    float* dis  = sq + 8192;                     // 8192
    float* pool = dis + 8192;                    // 32*1024
    float* f1   = pool + 32768;                  // 32*512
    float* f2   = f1 + 16384;                    // 32*128
    ushort_t* X1st = X0lo;                       // alias
    ushort_t* X2b  = X0st;                       // alias

    wconv_kernel<<<48, 256, 0, stream>>>(W1, Wt, 6, 128, 32, 12288);
    wconv_kernel<<<768, 256, 0, stream>>>(W2, Wt + 12288, 128, 512, 128, 196608);
    wconv_kernel<<<6144, 256, 0, stream>>>(W3, Wt + 208896, 512, 1024, 512, 1572864);
    zero_kernel<<<128, 256, 0, stream>>>(pool, 32768);

    for (int c = 0; c < NCHUNK; ++c) {
        int b0 = c * BC;
        struct LayerDef {
            const float* X; int F, Fp, Fo;
            const ushort_t* Wtl; const float* bias; float* O;
        };
        LayerDef L[3] = {
            { x + (size_t)b0 * NN * 6, 6,   32,  128,  Wt,          b1, O1 },
            { O1,                      128, 128, 512,  Wt + 12288,  b2, O2 },
            { O2,                      512, 512, 1024, Wt + 208896, b3, nullptr },
        };
        for (int li = 0; li < 3; ++li) {
            LayerDef& Ld = L[li];
            int F = Ld.F, Fp = Ld.Fp;
            prep_kernel<<<2048, 256, 0, stream>>>(Ld.X, X0hi, X0lo, sq, F, Fp);
            adj_kernel<<<dim3(8, 8, BC), 256, 0, stream>>>(X0hi, X0lo, sq, Abf, Fp);
            degdis_kernel<<<2048, 256, 0, stream>>>(Abf, dis);
            scaleT_kernel<<<dim3(16, (F + 63) / 64, BC), 256, 0, stream>>>(Ld.X, dis, X0st, F, Fp);
            lx_kernel<<<dim3((F + 127) / 128, 8, BC), 256, 0, stream>>>(
                Abf, dis, X0st, nullptr, X1st, F, Fp, 0);
            trT_kernel<<<dim3(16, (Fp + 63) / 64, BC), 256, 0, stream>>>(X1st, dis, X1b, F, Fp, 1);
            lx_kernel<<<dim3((F + 127) / 128, 8, BC), 256, 0, stream>>>(
                Abf, dis, X1st, X0st, X2bt, F, Fp, 1);
            trT_kernel<<<dim3(16, (Fp + 63) / 64, BC), 256, 0, stream>>>(X2bt, dis, X2b, F, Fp, 0);
            proj_kernel<<<dim3(Ld.Fo / 128, 64), 256, 0, stream>>>(
                X0hi, X1b, X2b, Ld.Wtl, Ld.bias, Ld.O, pool, Fp, Ld.Fo, b0);
        }
    }

    fc_kernel<<<64, 256, 0, stream>>>(pool, fc1w, fc1b, f1, 1024, 512, 1);
    fc_kernel<<<16, 256, 0, stream>>>(f1, fc2w, fc2b, f2, 512, 128, 1);
    fc_kernel<<<5, 256, 0, stream>>>(f2, fc3w, fc3b, out, 128, 40, 0);
}

// Round 4
// 2078.149 us; speedup vs baseline: 3.3993x; 1.1767x over previous
//
#include <hip/hip_runtime.h>
#include <cstddef>

// ---------------------------------------------------------------------------
// ChebNet on MFMA bf16: B=32, N=1024, layers 6->128->512->1024 (K_cheb=3),
// maxpool, FC 1024->512->128->40.  Batch-chunked 4 x 8 samples (~84 MB ws).
// - adjacency: split-bf16 (hi+lo) MFMA NT-GEMM + exp epilogue -> A bf16
// - L*X: MFMA using A's symmetry (both operands k-contiguous), Laplacian fused
// - proj: MFMA over 3 stacked K segments, bias+relu fused; layer-3 maxpool fused
// - fc: K-parallel (4 slices x 64 cols per block) + LDS reduce
// ---------------------------------------------------------------------------

#define NN 1024
#define BC 8
#define NCHUNK 4

typedef unsigned short ushort_t;
typedef __bf16 bf16x8 __attribute__((ext_vector_type(8)));
typedef float f32x4 __attribute__((ext_vector_type(4)));

__device__ inline ushort_t f2bf(float f) {
    unsigned int u = __float_as_uint(f);
    u = (u + 0x7fffu + ((u >> 16) & 1u)) >> 16;
    return (ushort_t)u;
}
__device__ inline float bf2f(ushort_t s) {
    return __uint_as_float(((unsigned int)s) << 16);
}

__global__ void zero_kernel(float* __restrict__ p, int n) {
    int i = blockIdx.x * blockDim.x + threadIdx.x;
    if (i < n) p[i] = 0.f;
}

// W[p][Fi][Fo] fp32 -> Wt[p][Fo][Ks] bf16 (transposed, K zero-padded to Ks)
__global__ void wconv_kernel(const float* __restrict__ W, ushort_t* __restrict__ Wt,
                             int Fi, int Fo, int Ks, int total) {
    int idx = blockIdx.x * blockDim.x + threadIdx.x;
    if (idx >= total) return;
    int kk = idx % Ks;
    int rest = idx / Ks;
    int g = rest % Fo;
    int p = rest / Fo;
    float v = (kk < Fi) ? W[((size_t)p * Fi + kk) * Fo + g] : 0.f;
    Wt[idx] = f2bf(v);
}

// per row: hi/lo bf16 split (padded to Fp with zeros) + squared norm
__global__ __launch_bounds__(256) void prep_kernel(
    const float* __restrict__ X, ushort_t* __restrict__ hi, ushort_t* __restrict__ lo,
    float* __restrict__ sq, int F, int Fp) {
    int t = threadIdx.x;
    int row = blockIdx.x * 4 + (t >> 6);
    int lane = t & 63;
    const float* Xr = X + (size_t)row * F;
    float s = 0.f;
    for (int f = lane; f < Fp; f += 64) {
        float x = (f < F) ? Xr[f] : 0.f;
        ushort_t h = f2bf(x);
        float l = x - bf2f(h);
        hi[(size_t)row * Fp + f] = h;
        lo[(size_t)row * Fp + f] = f2bf(l);
        s += x * x;
    }
#pragma unroll
    for (int off = 32; off > 0; off >>= 1) s += __shfl_down(s, off);
    if (lane == 0) sq[row] = s;
}

// A[b,n,m] = exp(2*x_n.x_m - sq_n - sq_m) -> bf16, split-precision MFMA
__global__ __launch_bounds__(256) void adj_kernel(
    const ushort_t* __restrict__ hi, const ushort_t* __restrict__ lo,
    const float* __restrict__ sq, ushort_t* __restrict__ Abf, int Fp) {
    int t = threadIdx.x;
    int m0 = blockIdx.x * 128, n0 = blockIdx.y * 128, b = blockIdx.z;
    const ushort_t* Hb = hi + (size_t)b * NN * Fp;
    const ushort_t* Lb = lo + (size_t)b * NN * Fp;
    ushort_t* Ab = Abf + (size_t)b * NN * NN;
    const float* sqb = sq + (size_t)b * NN;

    int lane = t & 63, quad = lane >> 4, l16 = lane & 15, wave = t >> 6;
    int rowoff = (wave >> 1) * 64, coloff = (wave & 1) * 64;

    __shared__ __align__(16) ushort_t Ah[128][40];
    __shared__ __align__(16) ushort_t Al[128][40];
    __shared__ __align__(16) ushort_t Bh[128][40];
    __shared__ __align__(16) ushort_t Bl[128][40];

    f32x4 acc[4][4];
#pragma unroll
    for (int i = 0; i < 4; ++i)
#pragma unroll
        for (int j = 0; j < 4; ++j) acc[i][j] = (f32x4){0.f, 0.f, 0.f, 0.f};

    for (int k0 = 0; k0 < Fp; k0 += 32) {
        for (int s = t; s < 512; s += 256) {
            int rr = s >> 2, kq = (s & 3) * 8;
            *(uint4*)&Ah[rr][kq] = *(const uint4*)(Hb + (size_t)(n0 + rr) * Fp + k0 + kq);
            *(uint4*)&Al[rr][kq] = *(const uint4*)(Lb + (size_t)(n0 + rr) * Fp + k0 + kq);
            *(uint4*)&Bh[rr][kq] = *(const uint4*)(Hb + (size_t)(m0 + rr) * Fp + k0 + kq);
            *(uint4*)&Bl[rr][kq] = *(const uint4*)(Lb + (size_t)(m0 + rr) * Fp + k0 + kq);
        }
        __syncthreads();
        bf16x8 ah[4], al[4], bh[4], bl[4];
#pragma unroll
        for (int i = 0; i < 4; ++i) {
            ah[i] = *(const bf16x8*)&Ah[rowoff + i * 16 + l16][quad * 8];
            al[i] = *(const bf16x8*)&Al[rowoff + i * 16 + l16][quad * 8];
        }
#pragma unroll
        for (int j = 0; j < 4; ++j) {
            bh[j] = *(const bf16x8*)&Bh[coloff + j * 16 + l16][quad * 8];
            bl[j] = *(const bf16x8*)&Bl[coloff + j * 16 + l16][quad * 8];
        }
#pragma unroll
        for (int i = 0; i < 4; ++i)
#pragma unroll
            for (int j = 0; j < 4; ++j) {
                acc[i][j] = __builtin_amdgcn_mfma_f32_16x16x32_bf16(al[i], bh[j], acc[i][j], 0, 0, 0);
                acc[i][j] = __builtin_amdgcn_mfma_f32_16x16x32_bf16(ah[i], bl[j], acc[i][j], 0, 0, 0);
                acc[i][j] = __builtin_amdgcn_mfma_f32_16x16x32_bf16(ah[i], bh[j], acc[i][j], 0, 0, 0);
            }
        __syncthreads();
    }
#pragma unroll
    for (int j = 0; j < 4; ++j) {
        int m = m0 + coloff + j * 16 + l16;
        float sm = sqb[m];
#pragma unroll
        for (int i = 0; i < 4; ++i) {
#pragma unroll
            for (int r = 0; r < 4; ++r) {
                int n = n0 + rowoff + i * 16 + quad * 4 + r;
                float v = __expf(2.f * acc[i][j][r] - sqb[n] - sm);
                Ab[(size_t)n * NN + m] = f2bf(v);
            }
        }
    }
}

// dis[row] = rsqrt(rowsum(A[row,:]))
__global__ __launch_bounds__(256) void degdis_kernel(const ushort_t* __restrict__ Abf,
                                                     float* __restrict__ dis) {
    int t = threadIdx.x;
    int row = blockIdx.x * 4 + (t >> 6);
    int lane = t & 63;
    const ushort_t* Ar = Abf + (size_t)row * NN + lane * 16;
    uint4 v1 = *(const uint4*)Ar;
    uint4 v2 = *(const uint4*)(Ar + 8);
    float s = 0.f;
    const unsigned int* w1 = (const unsigned int*)&v1;
    const unsigned int* w2 = (const unsigned int*)&v2;
#pragma unroll
    for (int i = 0; i < 4; ++i) {
        s += bf2f((ushort_t)(w1[i] & 0xffff)) + bf2f((ushort_t)(w1[i] >> 16));
        s += bf2f((ushort_t)(w2[i] & 0xffff)) + bf2f((ushort_t)(w2[i] >> 16));
    }
#pragma unroll
    for (int off = 32; off > 0; off >>= 1) s += __shfl_down(s, off);
    if (lane == 0) dis[row] = rsqrtf(s);
}

// X fp32 [b*N+n][F] -> Xst bf16 [b][f][n] scaled by dis[n]
__global__ __launch_bounds__(256) void scaleT_kernel(
    const float* __restrict__ X, const float* __restrict__ dis,
    ushort_t* __restrict__ Xst, int F, int Fp) {
    int t = threadIdx.x;
    int n0 = blockIdx.x * 64, f0 = blockIdx.y * 64, b = blockIdx.z;
    __shared__ float T[64][65];
    const float* Xb = X + (size_t)(b * NN + n0) * F;
#pragma unroll
    for (int p = 0; p < 16; ++p) {
        int nr = (t >> 6) + 4 * p;
        int f = f0 + (t & 63);
        T[nr][t & 63] = (f < F) ? Xb[(size_t)nr * F + f] : 0.f;
    }
    __syncthreads();
    float dl = dis[(size_t)b * NN + n0 + (t & 63)];
#pragma unroll
    for (int p = 0; p < 16; ++p) {
        int fr = (t >> 6) + 4 * p;
        int f = f0 + fr;
        if (f < F)
            Xst[((size_t)b * Fp + f) * NN + n0 + (t & 63)] = f2bf(T[t & 63][fr] * dl);
    }
}

// transposed st [b][f][n] -> row-major [b*N+n][Fp] (zero pad f>=F), optional /dis[n]
__global__ __launch_bounds__(256) void trT_kernel(
    const ushort_t* __restrict__ src, const float* __restrict__ dis,
    ushort_t* __restrict__ dst, int F, int Fp, int inv) {
    int t = threadIdx.x;
    int n0 = blockIdx.x * 64, f0 = blockIdx.y * 64, b = blockIdx.z;
    __shared__ ushort_t T[64][66];
#pragma unroll
    for (int p = 0; p < 16; ++p) {
        int fr = (t >> 6) + 4 * p;
        int f = f0 + fr;
        ushort_t v = 0;
        if (f < F) v = src[((size_t)b * Fp + f) * NN + n0 + (t & 63)];
        T[fr][t & 63] = v;
    }
    __syncthreads();
    int f = f0 + (t & 63);
    if (f >= Fp) return;
#pragma unroll
    for (int p = 0; p < 16; ++p) {
        int nr = (t >> 6) + 4 * p;
        int n = n0 + nr;
        float sc = inv ? (1.f / dis[(size_t)b * NN + n]) : 1.f;
        float val = (f < F) ? bf2f(T[t & 63][nr]) * sc : 0.f;
        dst[((size_t)b * NN + n) * Fp + f] = f2bf(val);
    }
}

// transposed-space L*X: acc[f][n] = sum_k in_st[f][k]*A[k][n]  (A symmetric)
// mode0: out = X0st - dn^2*acc      ( = dn*X1t, i.e. next scaled operand)
// mode1: out = (2*X1st - X0st)/dn - 2*dn*acc  ( = X2t )
__global__ __launch_bounds__(256) void lx_kernel(
    const ushort_t* __restrict__ Abf, const float* __restrict__ dis,
    const ushort_t* __restrict__ in_st, const ushort_t* __restrict__ aux_st,
    ushort_t* __restrict__ out_st, int F, int Fp, int mode) {
    int t = threadIdx.x;
    int m0 = blockIdx.x * 128, n0 = blockIdx.y * 128, b = blockIdx.z;
    const ushort_t* Ain = in_st + (size_t)b * Fp * NN;
    const ushort_t* Ab = Abf + (size_t)b * NN * NN;

    int lane = t & 63, quad = lane >> 4, l16 = lane & 15, wave = t >> 6;
    int rowoff = (wave >> 1) * 64, coloff = (wave & 1) * 64;

    __shared__ __align__(16) ushort_t As[128][40];
    __shared__ __align__(16) ushort_t Bs[128][40];
    f32x4 acc[4][4];
#pragma unroll
    for (int i = 0; i < 4; ++i)
#pragma unroll
        for (int j = 0; j < 4; ++j) acc[i][j] = (f32x4){0.f, 0.f, 0.f, 0.f};

    for (int k0 = 0; k0 < NN; k0 += 32) {
        for (int s = t; s < 512; s += 256) {
            int rr = s >> 2, kq = (s & 3) * 8;
            uint4 v = make_uint4(0u, 0u, 0u, 0u);
            if (m0 + rr < F) v = *(const uint4*)(Ain + (size_t)(m0 + rr) * NN + k0 + kq);
            *(uint4*)&As[rr][kq] = v;
            *(uint4*)&Bs[rr][kq] = *(const uint4*)(Ab + (size_t)(n0 + rr) * NN + k0 + kq);
        }
        __syncthreads();
        bf16x8 af[4], bf[4];
#pragma unroll
        for (int i = 0; i < 4; ++i) af[i] = *(const bf16x8*)&As[rowoff + i * 16 + l16][quad * 8];
#pragma unroll
        for (int j = 0; j < 4; ++j) bf[j] = *(const bf16x8*)&Bs[coloff + j * 16 + l16][quad * 8];
#pragma unroll
        for (int i = 0; i < 4; ++i)
#pragma unroll
            for (int j = 0; j < 4; ++j)
                acc[i][j] = __builtin_amdgcn_mfma_f32_16x16x32_bf16(af[i], bf[j], acc[i][j], 0, 0, 0);
        __syncthreads();
    }
#pragma unroll
    for (int j = 0; j < 4; ++j) {
        int n = n0 + coloff + j * 16 + l16;
        float dn = dis[(size_t)b * NN + n];
        float inv = mode ? (1.f / dn) : 0.f;
        float dn2 = dn * dn;
#pragma unroll
        for (int i = 0; i < 4; ++i) {
#pragma unroll
            for (int r = 0; r < 4; ++r) {
                int f = m0 + rowoff + i * 16 + quad * 4 + r;
                if (f < F) {
                    size_t off = ((size_t)b * Fp + f) * NN + n;
                    float a = acc[i][j][r];
                    float xin = bf2f(in_st[off]);
                    float o;
                    if (mode == 0) {
                        o = xin - dn2 * a;
                    } else {
                        float x0 = bf2f(aux_st[off]);
                        o = inv * (2.f * xin - x0) - 2.f * dn * a;
                    }
                    out_st[off] = f2bf(o);
                }
            }
        }
    }
}

// Out[r][g] = relu( sum_p Xp[r][:]*Wt[p][g][:] + bias[g] ); layer3: fused maxpool
__global__ __launch_bounds__(256) void proj_kernel(
    const ushort_t* __restrict__ X0, const ushort_t* __restrict__ X1,
    const ushort_t* __restrict__ X2, const ushort_t* __restrict__ Wt,
    const float* __restrict__ bias, float* __restrict__ O, float* __restrict__ pool,
    int Fp, int Fo, int b0) {
    int t = threadIdx.x;
    int g0 = blockIdx.x * 128, r0 = blockIdx.y * 128;
    int lane = t & 63, quad = lane >> 4, l16 = lane & 15, wave = t >> 6;
    int rowoff = (wave >> 1) * 64, coloff = (wave & 1) * 64;

    __shared__ __align__(16) ushort_t As[128][40];
    __shared__ __align__(16) ushort_t Bs[128][40];
    f32x4 acc[4][4];
#pragma unroll
    for (int i = 0; i < 4; ++i)
#pragma unroll
        for (int j = 0; j < 4; ++j) acc[i][j] = (f32x4){0.f, 0.f, 0.f, 0.f};

    const ushort_t* Xs[3] = {X0, X1, X2};
    for (int p = 0; p < 3; ++p) {
        const ushort_t* Xp = Xs[p];
        const ushort_t* Wp = Wt + (size_t)p * Fo * Fp;
        for (int k0 = 0; k0 < Fp; k0 += 32) {
            for (int s = t; s < 512; s += 256) {
                int rr = s >> 2, kq = (s & 3) * 8;
                *(uint4*)&As[rr][kq] = *(const uint4*)(Xp + (size_t)(r0 + rr) * Fp + k0 + kq);
                *(uint4*)&Bs[rr][kq] = *(const uint4*)(Wp + (size_t)(g0 + rr) * Fp + k0 + kq);
            }
            __syncthreads();
            bf16x8 af[4], bf[4];
#pragma unroll
            for (int i = 0; i < 4; ++i) af[i] = *(const bf16x8*)&As[rowoff + i * 16 + l16][quad * 8];
#pragma unroll
            for (int j = 0; j < 4; ++j) bf[j] = *(const bf16x8*)&Bs[coloff + j * 16 + l16][quad * 8];
#pragma unroll
            for (int i = 0; i < 4; ++i)
#pragma unroll
                for (int j = 0; j < 4; ++j)
                    acc[i][j] = __builtin_amdgcn_mfma_f32_16x16x32_bf16(af[i], bf[j], acc[i][j], 0, 0, 0);
            __syncthreads();
        }
    }

    float bias_l[4];
#pragma unroll
    for (int j = 0; j < 4; ++j) bias_l[j] = bias[g0 + coloff + j * 16 + l16];

    if (O) {
#pragma unroll
        for (int i = 0; i < 4; ++i) {
#pragma unroll
            for (int r = 0; r < 4; ++r) {
                int row = r0 + rowoff + i * 16 + quad * 4 + r;
#pragma unroll
                for (int j = 0; j < 4; ++j) {
                    int g = g0 + coloff + j * 16 + l16;
                    O[(size_t)row * Fo + g] = fmaxf(acc[i][j][r] + bias_l[j], 0.f);
                }
            }
        }
    } else {
        float mj[4];
#pragma unroll
        for (int j = 0; j < 4; ++j) {
            float m = 0.f;
#pragma unroll
            for (int i = 0; i < 4; ++i)
#pragma unroll
                for (int r = 0; r < 4; ++r)
                    m = fmaxf(m, acc[i][j][r] + bias_l[j]);
            m = fmaxf(m, 0.f);
            m = fmaxf(m, __shfl_xor(m, 16));
            m = fmaxf(m, __shfl_xor(m, 32));
            mj[j] = m;
        }
        if (quad == 0) {
            int smp = b0 + (r0 >> 10);
#pragma unroll
            for (int j = 0; j < 4; ++j)
                atomicMax((int*)&pool[(size_t)smp * 1024 + g0 + coloff + j * 16 + l16],
                          __float_as_int(mj[j]));
        }
    }
}

// fc: block = (row r, 64-col tile); 4 K-slices x 64 cols; LDS reduce.
__global__ __launch_bounds__(256) void fc_kernel(
    const float* __restrict__ In, const float* __restrict__ W,
    const float* __restrict__ bias, float* __restrict__ out,
    int K, int Nout, int relu) {
    int r = blockIdx.y;
    int c0 = blockIdx.x * 64;
    int t = threadIdx.x;
    int cl = t & 63, ks = t >> 6;
    int c = c0 + cl;
    int kchunk = K >> 2;
    int k0 = ks * kchunk, k1 = k0 + kchunk;
    float s = 0.f;
    if (c < Nout) {
        const float* ip = In + (size_t)r * K;
        const float* wp = W + c;
#pragma unroll 4
        for (int k = k0; k < k1; ++k) s += ip[k] * wp[(size_t)k * Nout];
    }
    __shared__ float red[4][64];
    red[ks][cl] = s;
    __syncthreads();
    if (t < 64 && c0 + t < Nout) {
        float v = red[0][t] + red[1][t] + red[2][t] + red[3][t] + bias[c0 + t];
        if (relu) v = fmaxf(v, 0.f);
        out[(size_t)r * Nout + c0 + t] = v;
    }
}

// ---------------------------------------------------------------------------
extern "C" void kernel_launch(void* const* d_in, const int* in_sizes, int n_in,
                              void* d_out, int out_size, void* d_ws, size_t ws_size,
                              hipStream_t stream) {
    const float* x    = (const float*)d_in[0];
    const float* W1   = (const float*)d_in[1];
    const float* b1   = (const float*)d_in[2];
    const float* W2   = (const float*)d_in[3];
    const float* b2   = (const float*)d_in[4];
    const float* W3   = (const float*)d_in[5];
    const float* b3   = (const float*)d_in[6];
    const float* fc1w = (const float*)d_in[7];
    const float* fc1b = (const float*)d_in[8];
    const float* fc2w = (const float*)d_in[9];
    const float* fc2b = (const float*)d_in[10];
    const float* fc3w = (const float*)d_in[11];
    const float* fc3b = (const float*)d_in[12];
    float* out = (float*)d_out;

    ushort_t* Abf  = (ushort_t*)d_ws;            // 8M elems (16 MiB)
    ushort_t* X0hi = Abf + (size_t)8 * 1024 * 1024;
    ushort_t* X0lo = X0hi + 4194304;             // aliases X1st (disjoint lifetime)
    ushort_t* X0st = X0lo + 4194304;             // aliases X2b  (disjoint lifetime)
    ushort_t* X2bt = X0st + 4194304;
    ushort_t* X1b  = X2bt + 4194304;
    ushort_t* Wt   = X1b + 4194304;              // 1781760 elems
    float* O1   = (float*)(Wt + 1781760);        // 8192*128
    float* O2   = O1 + 1048576;                  // 8192*512
    float* sq   = O2 + 4194304;                  // 8192
    float* dis  = sq + 8192;                     // 8192
    float* pool = dis + 8192;                    // 32*1024
    float* f1   = pool + 32768;                  // 32*512
    float* f2   = f1 + 16384;                    // 32*128
    ushort_t* X1st = X0lo;                       // alias
    ushort_t* X2b  = X0st;                       // alias

    wconv_kernel<<<48, 256, 0, stream>>>(W1, Wt, 6, 128, 32, 12288);
    wconv_kernel<<<768, 256, 0, stream>>>(W2, Wt + 12288, 128, 512, 128, 196608);
    wconv_kernel<<<6144, 256, 0, stream>>>(W3, Wt + 208896, 512, 1024, 512, 1572864);
    zero_kernel<<<128, 256, 0, stream>>>(pool, 32768);

    for (int c = 0; c < NCHUNK; ++c) {
        int b0 = c * BC;
        struct LayerDef {
            const float* X; int F, Fp, Fo;
            const ushort_t* Wtl; const float* bias; float* O;
        };
        LayerDef L[3] = {
            { x + (size_t)b0 * NN * 6, 6,   32,  128,  Wt,          b1, O1 },
            { O1,                      128, 128, 512,  Wt + 12288,  b2, O2 },
            { O2,                      512, 512, 1024, Wt + 208896, b3, nullptr },
        };
        for (int li = 0; li < 3; ++li) {
            LayerDef& Ld = L[li];
            int F = Ld.F, Fp = Ld.Fp;
            prep_kernel<<<2048, 256, 0, stream>>>(Ld.X, X0hi, X0lo, sq, F, Fp);
            adj_kernel<<<dim3(8, 8, BC), 256, 0, stream>>>(X0hi, X0lo, sq, Abf, Fp);
            degdis_kernel<<<2048, 256, 0, stream>>>(Abf, dis);
            scaleT_kernel<<<dim3(16, (F + 63) / 64, BC), 256, 0, stream>>>(Ld.X, dis, X0st, F, Fp);
            lx_kernel<<<dim3((F + 127) / 128, 8, BC), 256, 0, stream>>>(
                Abf, dis, X0st, nullptr, X1st, F, Fp, 0);
            trT_kernel<<<dim3(16, (Fp + 63) / 64, BC), 256, 0, stream>>>(X1st, dis, X1b, F, Fp, 1);
            lx_kernel<<<dim3((F + 127) / 128, 8, BC), 256, 0, stream>>>(
                Abf, dis, X1st, X0st, X2bt, F, Fp, 1);
            trT_kernel<<<dim3(16, (Fp + 63) / 64, BC), 256, 0, stream>>>(X2bt, dis, X2b, F, Fp, 0);
            proj_kernel<<<dim3(Ld.Fo / 128, 64), 256, 0, stream>>>(
                X0hi, X1b, X2b, Ld.Wtl, Ld.bias, Ld.O, pool, Fp, Ld.Fo, b0);
        }
    }

    fc_kernel<<<dim3(8, 32), 256, 0, stream>>>(pool, fc1w, fc1b, f1, 1024, 512, 1);
    fc_kernel<<<dim3(2, 32), 256, 0, stream>>>(f1, fc2w, fc2b, f2, 512, 128, 1);
    fc_kernel<<<dim3(1, 32), 256, 0, stream>>>(f2, fc3w, fc3b, out, 128, 40, 0);
}

// Round 5
// 1941.492 us; speedup vs baseline: 3.6386x; 1.0704x over previous
//
#include <hip/hip_runtime.h>
#include <cstddef>

// ---------------------------------------------------------------------------
// ChebNet MFMA bf16: B=32, N=1024, layers 6->128->512->1024 (K=3), maxpool,
// FC 1024->512->128->40. Chunked 4 x 8 samples (~83 MB ws).
// Pipeline/layer: zero(sq,deg) -> prep2(hi,lo,Xt,sq) -> adj(A bf16, deg)
//   -> scaleA(A := D A D in place) -> lx1(X1t + X1b) -> lx2(X2b) -> proj.
// ---------------------------------------------------------------------------

#define NN 1024
#define BC 8
#define NCHUNK 4

typedef unsigned short ushort_t;
typedef __bf16 bf16x8 __attribute__((ext_vector_type(8)));
typedef float f32x4 __attribute__((ext_vector_type(4)));

__device__ inline ushort_t f2bf(float f) {
    unsigned int u = __float_as_uint(f);
    u = (u + 0x7fffu + ((u >> 16) & 1u)) >> 16;
    return (ushort_t)u;
}
__device__ inline float bf2f(ushort_t s) {
    return __uint_as_float(((unsigned int)s) << 16);
}

__global__ void zero_kernel(float* __restrict__ p, int n) {
    int i = blockIdx.x * blockDim.x + threadIdx.x;
    if (i < n) p[i] = 0.f;
}

// W[p][Fi][Fo] fp32 -> Wt[p][Fo][Ks] bf16, LDS-tiled transpose, zero-pad K.
__global__ __launch_bounds__(256) void wconvT_kernel(
    const float* __restrict__ W, ushort_t* __restrict__ Wt, int Fi, int Fo, int Ks) {
    int p = blockIdx.z;
    int k0 = blockIdx.y * 64, g0 = blockIdx.x * 64;
    __shared__ float T[64][65];
    int t = threadIdx.x;
#pragma unroll
    for (int q = 0; q < 16; ++q) {
        int kr = (t >> 6) + 4 * q, gc = t & 63;
        int k = k0 + kr, g = g0 + gc;
        T[kr][gc] = (k < Fi && g < Fo) ? W[((size_t)p * Fi + k) * Fo + g] : 0.f;
    }
    __syncthreads();
#pragma unroll
    for (int q = 0; q < 16; ++q) {
        int gr = (t >> 6) + 4 * q, kc = t & 63;
        int g = g0 + gr, k = k0 + kc;
        if (g < Fo && k < Ks)
            Wt[((size_t)p * Fo + g) * Ks + k] = f2bf(T[kc][gr]);
    }
}

// Fused: hi/lo bf16 split (row-major, zero-pad to Fp), plain transpose Xt,
// sq partial sums (atomicAdd; sq pre-zeroed).
__global__ __launch_bounds__(256) void prep2_kernel(
    const float* __restrict__ X, ushort_t* __restrict__ hi, ushort_t* __restrict__ lo,
    ushort_t* __restrict__ Xt, float* __restrict__ sq, int F, int Fp) {
    int t = threadIdx.x;
    int n0 = blockIdx.x * 64, f0 = blockIdx.y * 64, b = blockIdx.z;
    __shared__ float T[64][65];
    __shared__ float red[4][64];
    const float* Xb = X + ((size_t)b * NN + n0) * F;
#pragma unroll
    for (int p = 0; p < 16; ++p) {
        int nr = (t >> 6) + 4 * p, fc = t & 63;
        int f = f0 + fc;
        T[nr][fc] = (f < F) ? Xb[(size_t)nr * F + f] : 0.f;
    }
    __syncthreads();
    // hi/lo row-major
#pragma unroll
    for (int p = 0; p < 16; ++p) {
        int nr = (t >> 6) + 4 * p, fc = t & 63;
        int f = f0 + fc;
        if (f < Fp) {
            float x = T[nr][fc];
            ushort_t h = f2bf(x);
            size_t off = ((size_t)b * NN + n0 + nr) * Fp + f;
            hi[off] = h;
            lo[off] = f2bf(x - bf2f(h));
        }
    }
    // Xt transposed [b][f][n]
#pragma unroll
    for (int p = 0; p < 16; ++p) {
        int fr = (t >> 6) + 4 * p;
        int f = f0 + fr;
        if (f < F)
            Xt[((size_t)b * Fp + f) * NN + n0 + (t & 63)] = f2bf(T[t & 63][fr]);
    }
    // sq partials
    {
        int nl = t & 63, fq = t >> 6;
        float s = 0.f;
#pragma unroll
        for (int fc = 0; fc < 16; ++fc) {
            float v = T[nl][fq * 16 + fc];
            s += v * v;
        }
        red[fq][nl] = s;
    }
    __syncthreads();
    if (t < 64)
        atomicAdd(&sq[(size_t)b * NN + n0 + t],
                  red[0][t] + red[1][t] + red[2][t] + red[3][t]);
}

// A[b,n,m] = exp(2 x_n.x_m - sq_n - sq_m) -> bf16 (split hi/lo MFMA);
// deg[b,n] += rowsum (fp32 atomics, pre-zeroed).
__global__ __launch_bounds__(256) void adj_kernel(
    const ushort_t* __restrict__ hi, const ushort_t* __restrict__ lo,
    const float* __restrict__ sq, ushort_t* __restrict__ Abf,
    float* __restrict__ deg, int Fp) {
    int t = threadIdx.x;
    int m0 = blockIdx.x * 128, n0 = blockIdx.y * 128, b = blockIdx.z;
    const ushort_t* Hb = hi + (size_t)b * NN * Fp;
    const ushort_t* Lb = lo + (size_t)b * NN * Fp;
    ushort_t* Ab = Abf + (size_t)b * NN * NN;
    const float* sqb = sq + (size_t)b * NN;
    float* degb = deg + (size_t)b * NN;

    int lane = t & 63, quad = lane >> 4, l16 = lane & 15, wave = t >> 6;
    int rowoff = (wave >> 1) * 64, coloff = (wave & 1) * 64;

    __shared__ __align__(16) ushort_t Ah[128][40];
    __shared__ __align__(16) ushort_t Al[128][40];
    __shared__ __align__(16) ushort_t Bh[128][40];
    __shared__ __align__(16) ushort_t Bl[128][40];

    f32x4 acc[4][4];
#pragma unroll
    for (int i = 0; i < 4; ++i)
#pragma unroll
        for (int j = 0; j < 4; ++j) acc[i][j] = (f32x4){0.f, 0.f, 0.f, 0.f};

    for (int k0 = 0; k0 < Fp; k0 += 32) {
        for (int s = t; s < 512; s += 256) {
            int rr = s >> 2, kq = (s & 3) * 8;
            *(uint4*)&Ah[rr][kq] = *(const uint4*)(Hb + (size_t)(n0 + rr) * Fp + k0 + kq);
            *(uint4*)&Al[rr][kq] = *(const uint4*)(Lb + (size_t)(n0 + rr) * Fp + k0 + kq);
            *(uint4*)&Bh[rr][kq] = *(const uint4*)(Hb + (size_t)(m0 + rr) * Fp + k0 + kq);
            *(uint4*)&Bl[rr][kq] = *(const uint4*)(Lb + (size_t)(m0 + rr) * Fp + k0 + kq);
        }
        __syncthreads();
        bf16x8 ah[4], al[4], bh[4], bl[4];
#pragma unroll
        for (int i = 0; i < 4; ++i) {
            ah[i] = *(const bf16x8*)&Ah[rowoff + i * 16 + l16][quad * 8];
            al[i] = *(const bf16x8*)&Al[rowoff + i * 16 + l16][quad * 8];
        }
#pragma unroll
        for (int j = 0; j < 4; ++j) {
            bh[j] = *(const bf16x8*)&Bh[coloff + j * 16 + l16][quad * 8];
            bl[j] = *(const bf16x8*)&Bl[coloff + j * 16 + l16][quad * 8];
        }
#pragma unroll
        for (int i = 0; i < 4; ++i)
#pragma unroll
            for (int j = 0; j < 4; ++j) {
                acc[i][j] = __builtin_amdgcn_mfma_f32_16x16x32_bf16(al[i], bh[j], acc[i][j], 0, 0, 0);
                acc[i][j] = __builtin_amdgcn_mfma_f32_16x16x32_bf16(ah[i], bl[j], acc[i][j], 0, 0, 0);
                acc[i][j] = __builtin_amdgcn_mfma_f32_16x16x32_bf16(ah[i], bh[j], acc[i][j], 0, 0, 0);
            }
        __syncthreads();
    }

    float rs[4][4];
#pragma unroll
    for (int i = 0; i < 4; ++i)
#pragma unroll
        for (int r = 0; r < 4; ++r) rs[i][r] = 0.f;

#pragma unroll
    for (int j = 0; j < 4; ++j) {
        int m = m0 + coloff + j * 16 + l16;
        float sm = sqb[m];
#pragma unroll
        for (int i = 0; i < 4; ++i) {
#pragma unroll
            for (int r = 0; r < 4; ++r) {
                int n = n0 + rowoff + i * 16 + quad * 4 + r;
                float v = __expf(2.f * acc[i][j][r] - sqb[n] - sm);
                Ab[(size_t)n * NN + m] = f2bf(v);
                rs[i][r] += v;
            }
        }
    }
#pragma unroll
    for (int i = 0; i < 4; ++i)
#pragma unroll
        for (int r = 0; r < 4; ++r) {
            float s = rs[i][r];
            s += __shfl_xor(s, 1);
            s += __shfl_xor(s, 2);
            s += __shfl_xor(s, 4);
            s += __shfl_xor(s, 8);
            if (l16 == 0)
                atomicAdd(&degb[n0 + rowoff + i * 16 + quad * 4 + r], s);
        }
}

// A := D A D in place (bf16), D = diag(rsqrt(deg)). Block: 4 rows.
__global__ __launch_bounds__(256) void scaleA_kernel(
    ushort_t* __restrict__ Abf, const float* __restrict__ deg) {
    int b = blockIdx.y;
    int n0 = blockIdx.x * 4;
    int t = threadIdx.x;
    __shared__ float dism[NN];
    const float* degb = deg + (size_t)b * NN;
    for (int m = t; m < NN; m += 256) dism[m] = rsqrtf(degb[m]);
    __syncthreads();
    int row = n0 + (t >> 6);
    float dn = dism[row];
    ushort_t* Ar = Abf + ((size_t)b * NN + row) * NN;
    int c = t & 63;
#pragma unroll
    for (int o = 0; o < 2; ++o) {
        int oct = c + o * 64;          // uint4 index within row (128 total)
        uint4 v = *(const uint4*)(Ar + oct * 8);
        unsigned* w = (unsigned*)&v;
        ushort_t outp[8];
#pragma unroll
        for (int q = 0; q < 4; ++q) {
            int m = oct * 8 + q * 2;
            float a0 = bf2f((ushort_t)(w[q] & 0xffff));
            float a1 = bf2f((ushort_t)(w[q] >> 16));
            outp[2 * q]     = f2bf(dn * a0 * dism[m]);
            outp[2 * q + 1] = f2bf(dn * a1 * dism[m + 1]);
        }
        *(uint4*)(Ar + oct * 8) = *(uint4*)outp;
    }
}

// lx: acc[f][n] = sum_k in_t[f][k] * Asc[n][k]  (Asc symmetric = D A D)
// mode0: o = in_t - acc = X1[n,f]; write X1t (st) + X1b (row-major, LDS transp)
// mode1: o = 2*(in_t - acc) - x0t = X2[n,f]; write X2b (row-major) only
__global__ __launch_bounds__(256) void lx_kernel(
    const ushort_t* __restrict__ Asc, const ushort_t* __restrict__ in_t,
    const ushort_t* __restrict__ x0t, ushort_t* __restrict__ out_t,
    ushort_t* __restrict__ out_b, int F, int Fp, int mode) {
    int t = threadIdx.x;
    int m0 = blockIdx.x * 128;   // f tile
    int n0 = blockIdx.y * 128;   // n tile
    int b = blockIdx.z;
    const ushort_t* Ain = in_t + (size_t)b * Fp * NN;
    const ushort_t* Ab = Asc + (size_t)b * NN * NN;

    int lane = t & 63, quad = lane >> 4, l16 = lane & 15, wave = t >> 6;
    int rowoff = (wave >> 1) * 64, coloff = (wave & 1) * 64;

    __shared__ __align__(16) ushort_t smem[16384];  // As|Bs in k-loop; T after
    ushort_t* AsP = smem;          // [128][40]
    ushort_t* BsP = smem + 5120;   // [128][40]

    f32x4 acc[4][4];
#pragma unroll
    for (int i = 0; i < 4; ++i)
#pragma unroll
        for (int j = 0; j < 4; ++j) acc[i][j] = (f32x4){0.f, 0.f, 0.f, 0.f};

    for (int k0 = 0; k0 < NN; k0 += 32) {
        for (int s = t; s < 512; s += 256) {
            int rr = s >> 2, kq = (s & 3) * 8;
            uint4 va = make_uint4(0u, 0u, 0u, 0u);
            if (m0 + rr < F) va = *(const uint4*)(Ain + (size_t)(m0 + rr) * NN + k0 + kq);
            *(uint4*)&AsP[rr * 40 + kq] = va;
            *(uint4*)&BsP[rr * 40 + kq] = *(const uint4*)(Ab + (size_t)(n0 + rr) * NN + k0 + kq);
        }
        __syncthreads();
        bf16x8 af[4], bf[4];
#pragma unroll
        for (int i = 0; i < 4; ++i)
            af[i] = *(const bf16x8*)&AsP[(rowoff + i * 16 + l16) * 40 + quad * 8];
#pragma unroll
        for (int j = 0; j < 4; ++j)
            bf[j] = *(const bf16x8*)&BsP[(coloff + j * 16 + l16) * 40 + quad * 8];
#pragma unroll
        for (int i = 0; i < 4; ++i)
#pragma unroll
            for (int j = 0; j < 4; ++j)
                acc[i][j] = __builtin_amdgcn_mfma_f32_16x16x32_bf16(af[i], bf[j], acc[i][j], 0, 0, 0);
        __syncthreads();
    }

    // epilogue: compute o, write st (mode0), stage T for row-major store
#pragma unroll
    for (int j = 0; j < 4; ++j) {
        int nl = coloff + j * 16 + l16;
        int n = n0 + nl;
#pragma unroll
        for (int i = 0; i < 4; ++i) {
#pragma unroll
            for (int r = 0; r < 4; ++r) {
                int fl = rowoff + i * 16 + quad * 4 + r;
                int f = m0 + fl;
                float o = 0.f;
                if (f < F) {
                    float a = acc[i][j][r];
                    size_t off = (size_t)f * NN + n;
                    float xin = bf2f(Ain[off]);
                    if (mode == 0) {
                        o = xin - a;
                        out_t[(size_t)b * Fp * NN + off] = f2bf(o);
                    } else {
                        float x0 = bf2f(x0t[(size_t)b * Fp * NN + off]);
                        o = 2.f * (xin - a) - x0;
                    }
                }
                smem[nl * 128 + (((fl >> 3) ^ (nl & 7)) << 3) + (fl & 7)] = f2bf(o);
            }
        }
    }
    __syncthreads();
    // coalesced row-major store: 128 rows x 16 octs
    for (int s2 = t; s2 < 2048; s2 += 256) {
        int nl = s2 >> 4, oct = s2 & 15;
        int fg = m0 + oct * 8;
        if (fg < Fp) {
            uint4 v = *(const uint4*)&smem[nl * 128 + ((oct ^ (nl & 7)) << 3)];
            *(uint4*)(out_b + ((size_t)b * NN + n0 + nl) * Fp + fg) = v;
        }
    }
}

// Out[r][g] = relu( sum_p Xp[r][:].Wt[p][g][:] + bias[g] ); layer3: fused maxpool
__global__ __launch_bounds__(256) void proj_kernel(
    const ushort_t* __restrict__ X0, const ushort_t* __restrict__ X1,
    const ushort_t* __restrict__ X2, const ushort_t* __restrict__ Wt,
    const float* __restrict__ bias, float* __restrict__ O, float* __restrict__ pool,
    int Fp, int Fo, int b0) {
    int t = threadIdx.x;
    int g0 = blockIdx.x * 128, r0 = blockIdx.y * 128;
    int lane = t & 63, quad = lane >> 4, l16 = lane & 15, wave = t >> 6;
    int rowoff = (wave >> 1) * 64, coloff = (wave & 1) * 64;

    __shared__ __align__(16) ushort_t As[128][40];
    __shared__ __align__(16) ushort_t Bs[128][40];
    f32x4 acc[4][4];
#pragma unroll
    for (int i = 0; i < 4; ++i)
#pragma unroll
        for (int j = 0; j < 4; ++j) acc[i][j] = (f32x4){0.f, 0.f, 0.f, 0.f};

    const ushort_t* Xs[3] = {X0, X1, X2};
    for (int p = 0; p < 3; ++p) {
        const ushort_t* Xp = Xs[p];
        const ushort_t* Wp = Wt + (size_t)p * Fo * Fp;
        for (int k0 = 0; k0 < Fp; k0 += 32) {
            for (int s = t; s < 512; s += 256) {
                int rr = s >> 2, kq = (s & 3) * 8;
                *(uint4*)&As[rr][kq] = *(const uint4*)(Xp + (size_t)(r0 + rr) * Fp + k0 + kq);
                *(uint4*)&Bs[rr][kq] = *(const uint4*)(Wp + (size_t)(g0 + rr) * Fp + k0 + kq);
            }
            __syncthreads();
            bf16x8 af[4], bf[4];
#pragma unroll
            for (int i = 0; i < 4; ++i) af[i] = *(const bf16x8*)&As[rowoff + i * 16 + l16][quad * 8];
#pragma unroll
            for (int j = 0; j < 4; ++j) bf[j] = *(const bf16x8*)&Bs[coloff + j * 16 + l16][quad * 8];
#pragma unroll
            for (int i = 0; i < 4; ++i)
#pragma unroll
                for (int j = 0; j < 4; ++j)
                    acc[i][j] = __builtin_amdgcn_mfma_f32_16x16x32_bf16(af[i], bf[j], acc[i][j], 0, 0, 0);
            __syncthreads();
        }
    }

    float bias_l[4];
#pragma unroll
    for (int j = 0; j < 4; ++j) bias_l[j] = bias[g0 + coloff + j * 16 + l16];

    if (O) {
#pragma unroll
        for (int i = 0; i < 4; ++i) {
#pragma unroll
            for (int r = 0; r < 4; ++r) {
                int row = r0 + rowoff + i * 16 + quad * 4 + r;
#pragma unroll
                for (int j = 0; j < 4; ++j) {
                    int g = g0 + coloff + j * 16 + l16;
                    O[(size_t)row * Fo + g] = fmaxf(acc[i][j][r] + bias_l[j], 0.f);
                }
            }
        }
    } else {
        float mj[4];
#pragma unroll
        for (int j = 0; j < 4; ++j) {
            float m = 0.f;
#pragma unroll
            for (int i = 0; i < 4; ++i)
#pragma unroll
                for (int r = 0; r < 4; ++r)
                    m = fmaxf(m, acc[i][j][r] + bias_l[j]);
            m = fmaxf(m, 0.f);
            m = fmaxf(m, __shfl_xor(m, 16));
            m = fmaxf(m, __shfl_xor(m, 32));
            mj[j] = m;
        }
        if (quad == 0) {
            int smp = b0 + (r0 >> 10);
#pragma unroll
            for (int j = 0; j < 4; ++j)
                atomicMax((int*)&pool[(size_t)smp * 1024 + g0 + coloff + j * 16 + l16],
                          __float_as_int(mj[j]));
        }
    }
}

// fc: block = (row, 64-col tile); 4 K-slices x 64 cols; LDS reduce.
__global__ __launch_bounds__(256) void fc_kernel(
    const float* __restrict__ In, const float* __restrict__ W,
    const float* __restrict__ bias, float* __restrict__ out,
    int K, int Nout, int relu) {
    int r = blockIdx.y;
    int c0 = blockIdx.x * 64;
    int t = threadIdx.x;
    int cl = t & 63, ks = t >> 6;
    int c = c0 + cl;
    int kchunk = K >> 2;
    int k0 = ks * kchunk, k1 = k0 + kchunk;
    float s = 0.f;
    if (c < Nout) {
        const float* ip = In + (size_t)r * K;
        const float* wp = W + c;
#pragma unroll 4
        for (int k = k0; k < k1; ++k) s += ip[k] * wp[(size_t)k * Nout];
    }
    __shared__ float red[4][64];
    red[ks][cl] = s;
    __syncthreads();
    if (t < 64 && c0 + t < Nout) {
        float v = red[0][t] + red[1][t] + red[2][t] + red[3][t] + bias[c0 + t];
        if (relu) v = fmaxf(v, 0.f);
        out[(size_t)r * Nout + c0 + t] = v;
    }
}

// ---------------------------------------------------------------------------
extern "C" void kernel_launch(void* const* d_in, const int* in_sizes, int n_in,
                              void* d_out, int out_size, void* d_ws, size_t ws_size,
                              hipStream_t stream) {
    const float* x    = (const float*)d_in[0];
    const float* W1   = (const float*)d_in[1];
    const float* b1   = (const float*)d_in[2];
    const float* W2   = (const float*)d_in[3];
    const float* b2   = (const float*)d_in[4];
    const float* W3   = (const float*)d_in[5];
    const float* b3   = (const float*)d_in[6];
    const float* fc1w = (const float*)d_in[7];
    const float* fc1b = (const float*)d_in[8];
    const float* fc2w = (const float*)d_in[9];
    const float* fc2b = (const float*)d_in[10];
    const float* fc3w = (const float*)d_in[11];
    const float* fc3b = (const float*)d_in[12];
    float* out = (float*)d_out;

    const size_t SL = 4194304;                 // BC*NN*512 (max slab, ushorts)
    ushort_t* Abf  = (ushort_t*)d_ws;          // 8M ushorts (16 MiB)
    ushort_t* X0hi = Abf + (size_t)8 * 1024 * 1024;
    ushort_t* X0lo = X0hi + SL;                // aliases X2b (disjoint lifetime)
    ushort_t* X0t  = X0lo + SL;
    ushort_t* X1t  = X0t + SL;
    ushort_t* X1b  = X1t + SL;
    ushort_t* Wt   = X1b + SL;                 // 1781760 ushorts
    float* O1   = (float*)(Wt + 1781760);      // 8192*128
    float* O2   = O1 + 1048576;                // 8192*512
    float* sq   = O2 + 4194304;                // 8192
    float* deg  = sq + 8192;                   // 8192 (adjacent to sq!)
    float* pool = deg + 8192;                  // 32*1024
    float* f1   = pool + 32768;                // 32*512
    float* f2   = f1 + 16384;                  // 32*128
    ushort_t* X2b = X0lo;                      // alias

    wconvT_kernel<<<dim3(2, 1, 3), 256, 0, stream>>>(W1, Wt, 6, 128, 32);
    wconvT_kernel<<<dim3(8, 2, 3), 256, 0, stream>>>(W2, Wt + 12288, 128, 512, 128);
    wconvT_kernel<<<dim3(16, 8, 3), 256, 0, stream>>>(W3, Wt + 208896, 512, 1024, 512);
    zero_kernel<<<128, 256, 0, stream>>>(pool, 32768);

    for (int c = 0; c < NCHUNK; ++c) {
        int b0 = c * BC;
        struct LayerDef {
            const float* X; int F, Fp, Fo;
            const ushort_t* Wtl; const float* bias; float* O;
        };
        LayerDef L[3] = {
            { x + (size_t)b0 * NN * 6, 6,   32,  128,  Wt,          b1, O1 },
            { O1,                      128, 128, 512,  Wt + 12288,  b2, O2 },
            { O2,                      512, 512, 1024, Wt + 208896, b3, nullptr },
        };
        for (int li = 0; li < 3; ++li) {
            LayerDef& Ld = L[li];
            int F = Ld.F, Fp = Ld.Fp;
            int fpt = (Fp + 63) / 64, ft = (F + 127) / 128;
            zero_kernel<<<64, 256, 0, stream>>>(sq, 16384);  // sq + deg
            prep2_kernel<<<dim3(16, fpt, BC), 256, 0, stream>>>(
                Ld.X, X0hi, X0lo, X0t, sq, F, Fp);
            adj_kernel<<<dim3(8, 8, BC), 256, 0, stream>>>(X0hi, X0lo, sq, Abf, deg, Fp);
            scaleA_kernel<<<dim3(256, BC), 256, 0, stream>>>(Abf, deg);
            lx_kernel<<<dim3(ft, 8, BC), 256, 0, stream>>>(
                Abf, X0t, nullptr, X1t, X1b, F, Fp, 0);
            lx_kernel<<<dim3(ft, 8, BC), 256, 0, stream>>>(
                Abf, X1t, X0t, nullptr, X2b, F, Fp, 1);
            proj_kernel<<<dim3(Ld.Fo / 128, 64), 256, 0, stream>>>(
                X0hi, X1b, X2b, Ld.Wtl, Ld.bias, Ld.O, pool, Fp, Ld.Fo, b0);
        }
    }

    fc_kernel<<<dim3(8, 32), 256, 0, stream>>>(pool, fc1w, fc1b, f1, 1024, 512, 1);
    fc_kernel<<<dim3(2, 32), 256, 0, stream>>>(f1, fc2w, fc2b, f2, 512, 128, 1);
    fc_kernel<<<dim3(1, 32), 256, 0, stream>>>(f2, fc3w, fc3b, out, 128, 40, 0);
}

// Round 6
// 1929.530 us; speedup vs baseline: 3.6612x; 1.0062x over previous
//
#include <hip/hip_runtime.h>
#include <cstddef>

// ---------------------------------------------------------------------------
// ChebNet MFMA bf16: B=32, N=1024, layers 6->128->512->1024 (K=3), maxpool,
// FC 1024->512->128->40. Chunked 4 x 8 samples (~80 MB ws).
// Per layer: prep2(hi,lo,Xt,sq) -> adj(A bf16 + deg partials) -> scaleA(A:=DAD)
//   -> lx1(X1t+X1b) -> lx2(X2b) -> proj (bias+relu / fused maxpool).
// All heavy kernels use a 1D grid with XCD-aware decode (xcd = L & 7) so
// blocks sharing operand tiles land on the same XCD's L2.
// ---------------------------------------------------------------------------

#define NN 1024
#define BC 8
#define NCHUNK 4

typedef unsigned short ushort_t;
typedef __bf16 bf16x8 __attribute__((ext_vector_type(8)));
typedef float f32x4 __attribute__((ext_vector_type(4)));

__device__ inline ushort_t f2bf(float f) {
    unsigned int u = __float_as_uint(f);
    u = (u + 0x7fffu + ((u >> 16) & 1u)) >> 16;
    return (ushort_t)u;
}
__device__ inline float bf2f(ushort_t s) {
    return __uint_as_float(((unsigned int)s) << 16);
}

__global__ void zero_kernel(float* __restrict__ p, int n) {
    int i = blockIdx.x * blockDim.x + threadIdx.x;
    if (i < n) p[i] = 0.f;
}

// W[p][Fi][Fo] fp32 -> Wt[p][Fo][Ks] bf16, LDS-tiled transpose, zero-pad K.
__global__ __launch_bounds__(256) void wconvT_kernel(
    const float* __restrict__ W, ushort_t* __restrict__ Wt, int Fi, int Fo, int Ks) {
    int p = blockIdx.z;
    int k0 = blockIdx.y * 64, g0 = blockIdx.x * 64;
    __shared__ float T[64][65];
    int t = threadIdx.x;
#pragma unroll
    for (int q = 0; q < 16; ++q) {
        int kr = (t >> 6) + 4 * q, gc = t & 63;
        int k = k0 + kr, g = g0 + gc;
        T[kr][gc] = (k < Fi && g < Fo) ? W[((size_t)p * Fi + k) * Fo + g] : 0.f;
    }
    __syncthreads();
#pragma unroll
    for (int q = 0; q < 16; ++q) {
        int gr = (t >> 6) + 4 * q, kc = t & 63;
        int g = g0 + gr, k = k0 + kc;
        if (g < Fo && k < Ks)
            Wt[((size_t)p * Fo + g) * Ks + k] = f2bf(T[kc][gr]);
    }
}

// Fused: hi/lo bf16 split (row-major, zero-pad to Fp), transpose Xt, sq.
// 1D grid 16*BC: b = L&7, n0 = (L>>3)*64. Block loops all f-chunks.
__global__ __launch_bounds__(256) void prep2_kernel(
    const float* __restrict__ X, ushort_t* __restrict__ hi, ushort_t* __restrict__ lo,
    ushort_t* __restrict__ Xt, float* __restrict__ sq, int F, int Fp) {
    int L = blockIdx.x;
    int b = L & 7, n0 = (L >> 3) * 64;
    int t = threadIdx.x;
    __shared__ float T[64][65];
    __shared__ float red[4][64];
    const float* Xb = X + ((size_t)b * NN + n0) * F;
    float sacc = 0.f;

    for (int f0 = 0; f0 < Fp; f0 += 64) {
        __syncthreads();
#pragma unroll
        for (int p = 0; p < 16; ++p) {
            int nr = (t >> 6) + 4 * p, fc = t & 63;
            int f = f0 + fc;
            T[nr][fc] = (f < F) ? Xb[(size_t)nr * F + f] : 0.f;
        }
        __syncthreads();
#pragma unroll
        for (int p = 0; p < 16; ++p) {
            int nr = (t >> 6) + 4 * p, fc = t & 63;
            int f = f0 + fc;
            if (f < Fp) {
                float x = T[nr][fc];
                ushort_t h = f2bf(x);
                size_t off = ((size_t)b * NN + n0 + nr) * Fp + f;
                hi[off] = h;
                lo[off] = f2bf(x - bf2f(h));
            }
        }
#pragma unroll
        for (int p = 0; p < 16; ++p) {
            int fr = (t >> 6) + 4 * p;
            int f = f0 + fr;
            if (f < F)
                Xt[((size_t)b * Fp + f) * NN + n0 + (t & 63)] = f2bf(T[t & 63][fr]);
        }
        {
            int nl = t & 63, fq = t >> 6;
#pragma unroll
            for (int fc = 0; fc < 16; ++fc) {
                float v = T[nl][fq * 16 + fc];
                sacc += v * v;
            }
        }
    }
    red[t >> 6][t & 63] = sacc;
    __syncthreads();
    if (t < 64)
        sq[(size_t)b * NN + n0 + t] = red[0][t] + red[1][t] + red[2][t] + red[3][t];
}

// A[b,n,m] = exp(2 x_n.x_m - sq_n - sq_m) -> bf16 (split hi/lo MFMA);
// degree partials (no atomics): deg_part[slot][b][n], slot = m_tile*2+(wave&1).
// 1D grid 64*BC: b = L&7; rest = L>>3; m_tile = rest&7; n_tile = rest>>3.
__global__ __launch_bounds__(256) void adj_kernel(
    const ushort_t* __restrict__ hi, const ushort_t* __restrict__ lo,
    const float* __restrict__ sq, ushort_t* __restrict__ Abf,
    float* __restrict__ deg_part, int Fp) {
    int t = threadIdx.x;
    int L = blockIdx.x;
    int b = L & 7;
    int rest = L >> 3;
    int m0 = (rest & 7) * 128, n0 = (rest >> 3) * 128;
    const ushort_t* Hb = hi + (size_t)b * NN * Fp;
    const ushort_t* Lb = lo + (size_t)b * NN * Fp;
    ushort_t* Ab = Abf + (size_t)b * NN * NN;
    const float* sqb = sq + (size_t)b * NN;

    int lane = t & 63, quad = lane >> 4, l16 = lane & 15, wave = t >> 6;
    int rowoff = (wave >> 1) * 64, coloff = (wave & 1) * 64;

    __shared__ __align__(16) ushort_t Ah[128][40];
    __shared__ __align__(16) ushort_t Al[128][40];
    __shared__ __align__(16) ushort_t Bh[128][40];
    __shared__ __align__(16) ushort_t Bl[128][40];

    f32x4 acc[4][4];
#pragma unroll
    for (int i = 0; i < 4; ++i)
#pragma unroll
        for (int j = 0; j < 4; ++j) acc[i][j] = (f32x4){0.f, 0.f, 0.f, 0.f};

    for (int k0 = 0; k0 < Fp; k0 += 32) {
        for (int s = t; s < 512; s += 256) {
            int rr = s >> 2, kq = (s & 3) * 8;
            *(uint4*)&Ah[rr][kq] = *(const uint4*)(Hb + (size_t)(n0 + rr) * Fp + k0 + kq);
            *(uint4*)&Al[rr][kq] = *(const uint4*)(Lb + (size_t)(n0 + rr) * Fp + k0 + kq);
            *(uint4*)&Bh[rr][kq] = *(const uint4*)(Hb + (size_t)(m0 + rr) * Fp + k0 + kq);
            *(uint4*)&Bl[rr][kq] = *(const uint4*)(Lb + (size_t)(m0 + rr) * Fp + k0 + kq);
        }
        __syncthreads();
        bf16x8 ah[4], al[4], bh[4], bl[4];
#pragma unroll
        for (int i = 0; i < 4; ++i) {
            ah[i] = *(const bf16x8*)&Ah[rowoff + i * 16 + l16][quad * 8];
            al[i] = *(const bf16x8*)&Al[rowoff + i * 16 + l16][quad * 8];
        }
#pragma unroll
        for (int j = 0; j < 4; ++j) {
            bh[j] = *(const bf16x8*)&Bh[coloff + j * 16 + l16][quad * 8];
            bl[j] = *(const bf16x8*)&Bl[coloff + j * 16 + l16][quad * 8];
        }
#pragma unroll
        for (int i = 0; i < 4; ++i)
#pragma unroll
            for (int j = 0; j < 4; ++j) {
                acc[i][j] = __builtin_amdgcn_mfma_f32_16x16x32_bf16(al[i], bh[j], acc[i][j], 0, 0, 0);
                acc[i][j] = __builtin_amdgcn_mfma_f32_16x16x32_bf16(ah[i], bl[j], acc[i][j], 0, 0, 0);
                acc[i][j] = __builtin_amdgcn_mfma_f32_16x16x32_bf16(ah[i], bh[j], acc[i][j], 0, 0, 0);
            }
        __syncthreads();
    }

    float rs[4][4];
#pragma unroll
    for (int i = 0; i < 4; ++i)
#pragma unroll
        for (int r = 0; r < 4; ++r) rs[i][r] = 0.f;

#pragma unroll
    for (int j = 0; j < 4; ++j) {
        int m = m0 + coloff + j * 16 + l16;
        float sm = sqb[m];
#pragma unroll
        for (int i = 0; i < 4; ++i) {
#pragma unroll
            for (int r = 0; r < 4; ++r) {
                int n = n0 + rowoff + i * 16 + quad * 4 + r;
                float v = __expf(2.f * acc[i][j][r] - sqb[n] - sm);
                Ab[(size_t)n * NN + m] = f2bf(v);
                rs[i][r] += v;
            }
        }
    }
    int slot = (rest & 7) * 2 + (wave & 1);
#pragma unroll
    for (int i = 0; i < 4; ++i)
#pragma unroll
        for (int r = 0; r < 4; ++r) {
            float s = rs[i][r];
            s += __shfl_xor(s, 1);
            s += __shfl_xor(s, 2);
            s += __shfl_xor(s, 4);
            s += __shfl_xor(s, 8);
            if (l16 == 0)
                deg_part[((size_t)slot * BC + b) * NN + n0 + rowoff + i * 16 + quad * 4 + r] = s;
        }
}

// A := D A D in place (bf16); D = rsqrt(sum of 16 deg partials).
// 1D grid 16*BC: b = L&7, n0 = (L>>3)*64 (64 rows per block).
__global__ __launch_bounds__(256) void scaleA_kernel(
    ushort_t* __restrict__ Abf, const float* __restrict__ deg_part) {
    int L = blockIdx.x;
    int b = L & 7, n0 = (L >> 3) * 64;
    int t = threadIdx.x;
    __shared__ float dism[NN];
    for (int m = t; m < NN; m += 256) {
        float s = 0.f;
#pragma unroll
        for (int k = 0; k < 16; ++k) s += deg_part[((size_t)k * BC + b) * NN + m];
        dism[m] = rsqrtf(s);
    }
    __syncthreads();
    int c = t & 63;
#pragma unroll
    for (int rr = 0; rr < 16; ++rr) {
        int row = n0 + rr * 4 + (t >> 6);
        float dn = dism[row];
        ushort_t* Ar = Abf + ((size_t)b * NN + row) * NN;
#pragma unroll
        for (int o = 0; o < 2; ++o) {
            int oct = c + o * 64;
            uint4 v = *(const uint4*)(Ar + oct * 8);
            unsigned* w = (unsigned*)&v;
            ushort_t outp[8];
#pragma unroll
            for (int q = 0; q < 4; ++q) {
                int m = oct * 8 + q * 2;
                float a0 = bf2f((ushort_t)(w[q] & 0xffff));
                float a1 = bf2f((ushort_t)(w[q] >> 16));
                outp[2 * q]     = f2bf(dn * a0 * dism[m]);
                outp[2 * q + 1] = f2bf(dn * a1 * dism[m + 1]);
            }
            *(uint4*)(Ar + oct * 8) = *(uint4*)outp;
        }
    }
}

// lx: acc[f][n] = sum_k in_t[f][k] * Asc[n][k]  (Asc symmetric = D A D)
// mode0: o = in_t - acc = X1[n,f]; write X1t + X1b (row-major via LDS transp)
// mode1: o = 2*(in_t - acc) - x0t = X2[n,f]; write X2b only
// 1D grid ft*8*BC: b = L&7; rest = L>>3; f_tile = rest%ft; n_tile = rest/ft.
__global__ __launch_bounds__(256) void lx_kernel(
    const ushort_t* __restrict__ Asc, const ushort_t* __restrict__ in_t,
    const ushort_t* __restrict__ x0t, ushort_t* __restrict__ out_t,
    ushort_t* __restrict__ out_b, int F, int Fp, int mode, int ft) {
    int t = threadIdx.x;
    int L = blockIdx.x;
    int b = L & 7;
    int rest = L >> 3;
    int m0 = (rest % ft) * 128;   // f tile
    int n0 = (rest / ft) * 128;   // n tile
    const ushort_t* Ain = in_t + (size_t)b * Fp * NN;
    const ushort_t* Ab = Asc + (size_t)b * NN * NN;

    int lane = t & 63, quad = lane >> 4, l16 = lane & 15, wave = t >> 6;
    int rowoff = (wave >> 1) * 64, coloff = (wave & 1) * 64;

    __shared__ __align__(16) ushort_t smem[16384];  // As|Bs in k-loop; T after
    ushort_t* AsP = smem;          // [128][40]
    ushort_t* BsP = smem + 5120;   // [128][40]

    f32x4 acc[4][4];
#pragma unroll
    for (int i = 0; i < 4; ++i)
#pragma unroll
        for (int j = 0; j < 4; ++j) acc[i][j] = (f32x4){0.f, 0.f, 0.f, 0.f};

    for (int k0 = 0; k0 < NN; k0 += 32) {
        for (int s = t; s < 512; s += 256) {
            int rr = s >> 2, kq = (s & 3) * 8;
            uint4 va = make_uint4(0u, 0u, 0u, 0u);
            if (m0 + rr < F) va = *(const uint4*)(Ain + (size_t)(m0 + rr) * NN + k0 + kq);
            *(uint4*)&AsP[rr * 40 + kq] = va;
            *(uint4*)&BsP[rr * 40 + kq] = *(const uint4*)(Ab + (size_t)(n0 + rr) * NN + k0 + kq);
        }
        __syncthreads();
        bf16x8 af[4], bf[4];
#pragma unroll
        for (int i = 0; i < 4; ++i)
            af[i] = *(const bf16x8*)&AsP[(rowoff + i * 16 + l16) * 40 + quad * 8];
#pragma unroll
        for (int j = 0; j < 4; ++j)
            bf[j] = *(const bf16x8*)&BsP[(coloff + j * 16 + l16) * 40 + quad * 8];
#pragma unroll
        for (int i = 0; i < 4; ++i)
#pragma unroll
            for (int j = 0; j < 4; ++j)
                acc[i][j] = __builtin_amdgcn_mfma_f32_16x16x32_bf16(af[i], bf[j], acc[i][j], 0, 0, 0);
        __syncthreads();
    }

#pragma unroll
    for (int j = 0; j < 4; ++j) {
        int nl = coloff + j * 16 + l16;
        int n = n0 + nl;
#pragma unroll
        for (int i = 0; i < 4; ++i) {
#pragma unroll
            for (int r = 0; r < 4; ++r) {
                int fl = rowoff + i * 16 + quad * 4 + r;
                int f = m0 + fl;
                float o = 0.f;
                if (f < F) {
                    float a = acc[i][j][r];
                    size_t off = (size_t)f * NN + n;
                    float xin = bf2f(Ain[off]);
                    if (mode == 0) {
                        o = xin - a;
                        out_t[(size_t)b * Fp * NN + off] = f2bf(o);
                    } else {
                        float x0 = bf2f(x0t[(size_t)b * Fp * NN + off]);
                        o = 2.f * (xin - a) - x0;
                    }
                }
                smem[nl * 128 + (((fl >> 3) ^ (nl & 7)) << 3) + (fl & 7)] = f2bf(o);
            }
        }
    }
    __syncthreads();
    for (int s2 = t; s2 < 2048; s2 += 256) {
        int nl = s2 >> 4, oct = s2 & 15;
        int fg = m0 + oct * 8;
        if (fg < Fp) {
            uint4 v = *(const uint4*)&smem[nl * 128 + ((oct ^ (nl & 7)) << 3)];
            *(uint4*)(out_b + ((size_t)b * NN + n0 + nl) * Fp + fg) = v;
        }
    }
}

// Out[r][g] = relu( sum_p Xp[r][:].Wt[p][g][:] + bias[g] ); layer3: fused maxpool
// 1D grid n_g*64: c = L&7; rest = L>>3; g = rest%n_g; r_tile = c*8 + rest/n_g.
__global__ __launch_bounds__(256) void proj_kernel(
    const ushort_t* __restrict__ X0, const ushort_t* __restrict__ X1,
    const ushort_t* __restrict__ X2, const ushort_t* __restrict__ Wt,
    const float* __restrict__ bias, float* __restrict__ O, float* __restrict__ pool,
    int Fp, int Fo, int b0, int n_g) {
    int t = threadIdx.x;
    int L = blockIdx.x;
    int c = L & 7;
    int rest = L >> 3;
    int g0 = (rest % n_g) * 128;
    int r0 = (c * 8 + rest / n_g) * 128;
    int lane = t & 63, quad = lane >> 4, l16 = lane & 15, wave = t >> 6;
    int rowoff = (wave >> 1) * 64, coloff = (wave & 1) * 64;

    __shared__ __align__(16) ushort_t As[128][40];
    __shared__ __align__(16) ushort_t Bs[128][40];
    f32x4 acc[4][4];
#pragma unroll
    for (int i = 0; i < 4; ++i)
#pragma unroll
        for (int j = 0; j < 4; ++j) acc[i][j] = (f32x4){0.f, 0.f, 0.f, 0.f};

    const ushort_t* Xs[3] = {X0, X1, X2};
    for (int p = 0; p < 3; ++p) {
        const ushort_t* Xp = Xs[p];
        const ushort_t* Wp = Wt + (size_t)p * Fo * Fp;
        for (int k0 = 0; k0 < Fp; k0 += 32) {
            for (int s = t; s < 512; s += 256) {
                int rr = s >> 2, kq = (s & 3) * 8;
                *(uint4*)&As[rr][kq] = *(const uint4*)(Xp + (size_t)(r0 + rr) * Fp + k0 + kq);
                *(uint4*)&Bs[rr][kq] = *(const uint4*)(Wp + (size_t)(g0 + rr) * Fp + k0 + kq);
            }
            __syncthreads();
            bf16x8 af[4], bf[4];
#pragma unroll
            for (int i = 0; i < 4; ++i) af[i] = *(const bf16x8*)&As[rowoff + i * 16 + l16][quad * 8];
#pragma unroll
            for (int j = 0; j < 4; ++j) bf[j] = *(const bf16x8*)&Bs[coloff + j * 16 + l16][quad * 8];
#pragma unroll
            for (int i = 0; i < 4; ++i)
#pragma unroll
                for (int j = 0; j < 4; ++j)
                    acc[i][j] = __builtin_amdgcn_mfma_f32_16x16x32_bf16(af[i], bf[j], acc[i][j], 0, 0, 0);
            __syncthreads();
        }
    }

    float bias_l[4];
#pragma unroll
    for (int j = 0; j < 4; ++j) bias_l[j] = bias[g0 + coloff + j * 16 + l16];

    if (O) {
#pragma unroll
        for (int i = 0; i < 4; ++i) {
#pragma unroll
            for (int r = 0; r < 4; ++r) {
                int row = r0 + rowoff + i * 16 + quad * 4 + r;
#pragma unroll
                for (int j = 0; j < 4; ++j) {
                    int g = g0 + coloff + j * 16 + l16;
                    O[(size_t)row * Fo + g] = fmaxf(acc[i][j][r] + bias_l[j], 0.f);
                }
            }
        }
    } else {
        float mj[4];
#pragma unroll
        for (int j = 0; j < 4; ++j) {
            float m = 0.f;
#pragma unroll
            for (int i = 0; i < 4; ++i)
#pragma unroll
                for (int r = 0; r < 4; ++r)
                    m = fmaxf(m, acc[i][j][r] + bias_l[j]);
            m = fmaxf(m, 0.f);
            m = fmaxf(m, __shfl_xor(m, 16));
            m = fmaxf(m, __shfl_xor(m, 32));
            mj[j] = m;
        }
        if (quad == 0) {
            int smp = b0 + (r0 >> 10);
#pragma unroll
            for (int j = 0; j < 4; ++j)
                atomicMax((int*)&pool[(size_t)smp * 1024 + g0 + coloff + j * 16 + l16],
                          __float_as_int(mj[j]));
        }
    }
}

// fc: block = (row, 64-col tile); 4 K-slices x 64 cols; LDS reduce.
__global__ __launch_bounds__(256) void fc_kernel(
    const float* __restrict__ In, const float* __restrict__ W,
    const float* __restrict__ bias, float* __restrict__ out,
    int K, int Nout, int relu) {
    int r = blockIdx.y;
    int c0 = blockIdx.x * 64;
    int t = threadIdx.x;
    int cl = t & 63, ks = t >> 6;
    int c = c0 + cl;
    int kchunk = K >> 2;
    int k0 = ks * kchunk, k1 = k0 + kchunk;
    float s = 0.f;
    if (c < Nout) {
        const float* ip = In + (size_t)r * K;
        const float* wp = W + c;
#pragma unroll 4
        for (int k = k0; k < k1; ++k) s += ip[k] * wp[(size_t)k * Nout];
    }
    __shared__ float red[4][64];
    red[ks][cl] = s;
    __syncthreads();
    if (t < 64 && c0 + t < Nout) {
        float v = red[0][t] + red[1][t] + red[2][t] + red[3][t] + bias[c0 + t];
        if (relu) v = fmaxf(v, 0.f);
        out[(size_t)r * Nout + c0 + t] = v;
    }
}

// ---------------------------------------------------------------------------
extern "C" void kernel_launch(void* const* d_in, const int* in_sizes, int n_in,
                              void* d_out, int out_size, void* d_ws, size_t ws_size,
                              hipStream_t stream) {
    const float* x    = (const float*)d_in[0];
    const float* W1   = (const float*)d_in[1];
    const float* b1   = (const float*)d_in[2];
    const float* W2   = (const float*)d_in[3];
    const float* b2   = (const float*)d_in[4];
    const float* W3   = (const float*)d_in[5];
    const float* b3   = (const float*)d_in[6];
    const float* fc1w = (const float*)d_in[7];
    const float* fc1b = (const float*)d_in[8];
    const float* fc2w = (const float*)d_in[9];
    const float* fc2b = (const float*)d_in[10];
    const float* fc3w = (const float*)d_in[11];
    const float* fc3b = (const float*)d_in[12];
    float* out = (float*)d_out;

    const size_t SL = 4194304;                 // BC*NN*512 ushorts (max slab)
    ushort_t* Abf  = (ushort_t*)d_ws;          // 8M ushorts (16 MiB)
    ushort_t* X0hi = Abf + (size_t)8 * 1024 * 1024;
    ushort_t* X0lo = X0hi + SL;                // aliases X2b (disjoint lifetime)
    ushort_t* X0t  = X0lo + SL;
    ushort_t* X1t  = X0t + SL;
    ushort_t* X1b  = X1t + SL;
    ushort_t* Wt   = X1b + SL;                 // 1781760 ushorts
    float* O1   = (float*)(Wt + 1781760);      // 8192*128
    float* O2   = O1 + 1048576;                // 8192*512
    float* sq   = O2 + 4194304;                // 8192
    float* degp = sq + 8192;                   // 16*BC*NN = 131072
    float* pool = degp + 131072;               // 32*1024
    float* f1   = pool + 32768;                // 32*512
    float* f2   = f1 + 16384;                  // 32*128
    ushort_t* X2b = X0lo;                      // alias

    wconvT_kernel<<<dim3(2, 1, 3), 256, 0, stream>>>(W1, Wt, 6, 128, 32);
    wconvT_kernel<<<dim3(8, 2, 3), 256, 0, stream>>>(W2, Wt + 12288, 128, 512, 128);
    wconvT_kernel<<<dim3(16, 8, 3), 256, 0, stream>>>(W3, Wt + 208896, 512, 1024, 512);
    zero_kernel<<<128, 256, 0, stream>>>(pool, 32768);

    for (int c = 0; c < NCHUNK; ++c) {
        int b0 = c * BC;
        struct LayerDef {
            const float* X; int F, Fp, Fo;
            const ushort_t* Wtl; const float* bias; float* O;
        };
        LayerDef L[3] = {
            { x + (size_t)b0 * NN * 6, 6,   32,  128,  Wt,          b1, O1 },
            { O1,                      128, 128, 512,  Wt + 12288,  b2, O2 },
            { O2,                      512, 512, 1024, Wt + 208896, b3, nullptr },
        };
        for (int li = 0; li < 3; ++li) {
            LayerDef& Ld = L[li];
            int F = Ld.F, Fp = Ld.Fp;
            int ft = (F + 127) / 128;
            int n_g = Ld.Fo / 128;
            prep2_kernel<<<16 * BC, 256, 0, stream>>>(Ld.X, X0hi, X0lo, X0t, sq, F, Fp);
            adj_kernel<<<64 * BC, 256, 0, stream>>>(X0hi, X0lo, sq, Abf, degp, Fp);
            scaleA_kernel<<<16 * BC, 256, 0, stream>>>(Abf, degp);
            lx_kernel<<<ft * 8 * BC, 256, 0, stream>>>(
                Abf, X0t, nullptr, X1t, X1b, F, Fp, 0, ft);
            lx_kernel<<<ft * 8 * BC, 256, 0, stream>>>(
                Abf, X1t, X0t, nullptr, X2b, F, Fp, 1, ft);
            proj_kernel<<<n_g * 64, 256, 0, stream>>>(
                X0hi, X1b, X2b, Ld.Wtl, Ld.bias, Ld.O, pool, Fp, Ld.Fo, b0, n_g);
        }
    }

    fc_kernel<<<dim3(8, 32), 256, 0, stream>>>(pool, fc1w, fc1b, f1, 1024, 512, 1);
    fc_kernel<<<dim3(2, 32), 256, 0, stream>>>(f1, fc2w, fc2b, f2, 512, 128, 1);
    fc_kernel<<<dim3(1, 32), 256, 0, stream>>>(f2, fc3w, fc3b, out, 128, 40, 0);
}

// Round 7
// 1661.823 us; speedup vs baseline: 4.2510x; 1.1611x over previous
//
#include <hip/hip_runtime.h>
#include <cstddef>

// ---------------------------------------------------------------------------
// ChebNet MFMA bf16: B=32, N=1024, layers 6->128->512->1024 (K=3), maxpool,
// FC 1024->512->128->40. Chunked 4 x 8 samples (~80 MB ws).
// Per layer: prep2 -> adj -> scaleA -> lx1 -> lx2 -> proj.
// GEMM kernels are software-pipelined (2-stage LDS double buffer, one
// barrier/iter) to hide global-load latency at 1-block/CU occupancy.
// 1D grids with XCD-aware decode (xcd = L & 7) for L2 locality.
// ---------------------------------------------------------------------------

#define NN 1024
#define BC 8
#define NCHUNK 4

typedef unsigned short ushort_t;
typedef __bf16 bf16x8 __attribute__((ext_vector_type(8)));
typedef float f32x4 __attribute__((ext_vector_type(4)));

__device__ inline ushort_t f2bf(float f) {
    unsigned int u = __float_as_uint(f);
    u = (u + 0x7fffu + ((u >> 16) & 1u)) >> 16;
    return (ushort_t)u;
}
__device__ inline float bf2f(ushort_t s) {
    return __uint_as_float(((unsigned int)s) << 16);
}

__global__ void zero_kernel(float* __restrict__ p, int n) {
    int i = blockIdx.x * blockDim.x + threadIdx.x;
    if (i < n) p[i] = 0.f;
}

// W[p][Fi][Fo] fp32 -> Wt[p][Fo][Ks] bf16, LDS-tiled transpose, zero-pad K.
__global__ __launch_bounds__(256) void wconvT_kernel(
    const float* __restrict__ W, ushort_t* __restrict__ Wt, int Fi, int Fo, int Ks) {
    int p = blockIdx.z;
    int k0 = blockIdx.y * 64, g0 = blockIdx.x * 64;
    __shared__ float T[64][65];
    int t = threadIdx.x;
#pragma unroll
    for (int q = 0; q < 16; ++q) {
        int kr = (t >> 6) + 4 * q, gc = t & 63;
        int k = k0 + kr, g = g0 + gc;
        T[kr][gc] = (k < Fi && g < Fo) ? W[((size_t)p * Fi + k) * Fo + g] : 0.f;
    }
    __syncthreads();
#pragma unroll
    for (int q = 0; q < 16; ++q) {
        int gr = (t >> 6) + 4 * q, kc = t & 63;
        int g = g0 + gr, k = k0 + kc;
        if (g < Fo && k < Ks)
            Wt[((size_t)p * Fo + g) * Ks + k] = f2bf(T[kc][gr]);
    }
}

// Fused: hi/lo bf16 split (row-major, pad to Fp), transpose Xt, sq.
// 1D grid 16*BC: b = L&7, n0 = (L>>3)*64.
__global__ __launch_bounds__(256) void prep2_kernel(
    const float* __restrict__ X, ushort_t* __restrict__ hi, ushort_t* __restrict__ lo,
    ushort_t* __restrict__ Xt, float* __restrict__ sq, int F, int Fp) {
    int L = blockIdx.x;
    int b = L & 7, n0 = (L >> 3) * 64;
    int t = threadIdx.x;
    __shared__ float T[64][65];
    __shared__ float red[4][64];
    const float* Xb = X + ((size_t)b * NN + n0) * F;
    float sacc = 0.f;

    for (int f0 = 0; f0 < Fp; f0 += 64) {
        __syncthreads();
#pragma unroll
        for (int p = 0; p < 16; ++p) {
            int nr = (t >> 6) + 4 * p, fc = t & 63;
            int f = f0 + fc;
            T[nr][fc] = (f < F) ? Xb[(size_t)nr * F + f] : 0.f;
        }
        __syncthreads();
#pragma unroll
        for (int p = 0; p < 16; ++p) {
            int nr = (t >> 6) + 4 * p, fc = t & 63;
            int f = f0 + fc;
            if (f < Fp) {
                float x = T[nr][fc];
                ushort_t h = f2bf(x);
                size_t off = ((size_t)b * NN + n0 + nr) * Fp + f;
                hi[off] = h;
                lo[off] = f2bf(x - bf2f(h));
            }
        }
#pragma unroll
        for (int p = 0; p < 16; ++p) {
            int fr = (t >> 6) + 4 * p;
            int f = f0 + fr;
            if (f < F)
                Xt[((size_t)b * Fp + f) * NN + n0 + (t & 63)] = f2bf(T[t & 63][fr]);
        }
        {
            int nl = t & 63, fq = t >> 6;
#pragma unroll
            for (int fc = 0; fc < 16; ++fc) {
                float v = T[nl][fq * 16 + fc];
                sacc += v * v;
            }
        }
    }
    red[t >> 6][t & 63] = sacc;
    __syncthreads();
    if (t < 64)
        sq[(size_t)b * NN + n0 + t] = red[0][t] + red[1][t] + red[2][t] + red[3][t];
}

// A[b,n,m] = exp(2 x_n.x_m - sq_n - sq_m) -> bf16 (split hi/lo MFMA), dbuf;
// degree partials deg_part[slot][b][n], slot = m_tile*2+(wave&1).
// 1D grid 64*BC: b = L&7; rest = L>>3; m_tile = rest&7; n_tile = rest>>3.
__global__ __launch_bounds__(256) void adj_kernel(
    const ushort_t* __restrict__ hi, const ushort_t* __restrict__ lo,
    const float* __restrict__ sq, ushort_t* __restrict__ Abf,
    float* __restrict__ deg_part, int Fp) {
    int t = threadIdx.x;
    int L = blockIdx.x;
    int b = L & 7;
    int rest = L >> 3;
    int m0 = (rest & 7) * 128, n0 = (rest >> 3) * 128;
    const ushort_t* Hb = hi + (size_t)b * NN * Fp;
    const ushort_t* Lb = lo + (size_t)b * NN * Fp;
    ushort_t* Ab = Abf + (size_t)b * NN * NN;
    const float* sqb = sq + (size_t)b * NN;

    int lane = t & 63, quad = lane >> 4, l16 = lane & 15, wave = t >> 6;
    int rowoff = (wave >> 1) * 64, coloff = (wave & 1) * 64;

    // dbuf: 2 stages x 4 arrays x 5120 ushorts = 80 KB
    __shared__ __align__(16) ushort_t smem[40960];

    f32x4 acc[4][4];
#pragma unroll
    for (int i = 0; i < 4; ++i)
#pragma unroll
        for (int j = 0; j < 4; ++j) acc[i][j] = (f32x4){0.f, 0.f, 0.f, 0.f};

    int rr0 = t >> 2, kq = (t & 3) * 8;
    int rr1 = rr0 + 64;
    const ushort_t* pAh0 = Hb + (size_t)(n0 + rr0) * Fp + kq;
    const ushort_t* pAh1 = Hb + (size_t)(n0 + rr1) * Fp + kq;
    const ushort_t* pAl0 = Lb + (size_t)(n0 + rr0) * Fp + kq;
    const ushort_t* pAl1 = Lb + (size_t)(n0 + rr1) * Fp + kq;
    const ushort_t* pBh0 = Hb + (size_t)(m0 + rr0) * Fp + kq;
    const ushort_t* pBh1 = Hb + (size_t)(m0 + rr1) * Fp + kq;
    const ushort_t* pBl0 = Lb + (size_t)(m0 + rr0) * Fp + kq;
    const ushort_t* pBl1 = Lb + (size_t)(m0 + rr1) * Fp + kq;
    int o0 = rr0 * 40 + kq, o1 = rr1 * 40 + kq;

    // prologue: stage k=0 into buf0
    {
        *(uint4*)&smem[o0]         = *(const uint4*)pAh0;
        *(uint4*)&smem[o1]         = *(const uint4*)pAh1;
        *(uint4*)&smem[5120 + o0]  = *(const uint4*)pAl0;
        *(uint4*)&smem[5120 + o1]  = *(const uint4*)pAl1;
        *(uint4*)&smem[10240 + o0] = *(const uint4*)pBh0;
        *(uint4*)&smem[10240 + o1] = *(const uint4*)pBh1;
        *(uint4*)&smem[15360 + o0] = *(const uint4*)pBl0;
        *(uint4*)&smem[15360 + o1] = *(const uint4*)pBl1;
    }
    __syncthreads();

    int NIT = Fp >> 5;
    for (int it = 0; it < NIT; ++it) {
        int cur = (it & 1) * 20480;
        int nxt = 20480 - cur;
        uint4 rh0, rh1, rl0, rl1, sh0, sh1, sl0, sl1;
        if (it + 1 < NIT) {
            int k = (it + 1) * 32;
            rh0 = *(const uint4*)(pAh0 + k); rh1 = *(const uint4*)(pAh1 + k);
            rl0 = *(const uint4*)(pAl0 + k); rl1 = *(const uint4*)(pAl1 + k);
            sh0 = *(const uint4*)(pBh0 + k); sh1 = *(const uint4*)(pBh1 + k);
            sl0 = *(const uint4*)(pBl0 + k); sl1 = *(const uint4*)(pBl1 + k);
        }
        ushort_t* Ah = smem + cur;
        ushort_t* Al = smem + cur + 5120;
        ushort_t* Bh = smem + cur + 10240;
        ushort_t* Bl = smem + cur + 15360;
        bf16x8 ah[4], al[4], bh[4], bl[4];
#pragma unroll
        for (int i = 0; i < 4; ++i) {
            ah[i] = *(const bf16x8*)&Ah[(rowoff + i * 16 + l16) * 40 + quad * 8];
            al[i] = *(const bf16x8*)&Al[(rowoff + i * 16 + l16) * 40 + quad * 8];
        }
#pragma unroll
        for (int j = 0; j < 4; ++j) {
            bh[j] = *(const bf16x8*)&Bh[(coloff + j * 16 + l16) * 40 + quad * 8];
            bl[j] = *(const bf16x8*)&Bl[(coloff + j * 16 + l16) * 40 + quad * 8];
        }
#pragma unroll
        for (int i = 0; i < 4; ++i)
#pragma unroll
            for (int j = 0; j < 4; ++j) {
                acc[i][j] = __builtin_amdgcn_mfma_f32_16x16x32_bf16(al[i], bh[j], acc[i][j], 0, 0, 0);
                acc[i][j] = __builtin_amdgcn_mfma_f32_16x16x32_bf16(ah[i], bl[j], acc[i][j], 0, 0, 0);
                acc[i][j] = __builtin_amdgcn_mfma_f32_16x16x32_bf16(ah[i], bh[j], acc[i][j], 0, 0, 0);
            }
        if (it + 1 < NIT) {
            *(uint4*)&smem[nxt + o0]         = rh0;
            *(uint4*)&smem[nxt + o1]         = rh1;
            *(uint4*)&smem[nxt + 5120 + o0]  = rl0;
            *(uint4*)&smem[nxt + 5120 + o1]  = rl1;
            *(uint4*)&smem[nxt + 10240 + o0] = sh0;
            *(uint4*)&smem[nxt + 10240 + o1] = sh1;
            *(uint4*)&smem[nxt + 15360 + o0] = sl0;
            *(uint4*)&smem[nxt + 15360 + o1] = sl1;
        }
        __syncthreads();
    }

    float rs[4][4];
#pragma unroll
    for (int i = 0; i < 4; ++i)
#pragma unroll
        for (int r = 0; r < 4; ++r) rs[i][r] = 0.f;

#pragma unroll
    for (int j = 0; j < 4; ++j) {
        int m = m0 + coloff + j * 16 + l16;
        float sm = sqb[m];
#pragma unroll
        for (int i = 0; i < 4; ++i) {
#pragma unroll
            for (int r = 0; r < 4; ++r) {
                int n = n0 + rowoff + i * 16 + quad * 4 + r;
                float v = __expf(2.f * acc[i][j][r] - sqb[n] - sm);
                Ab[(size_t)n * NN + m] = f2bf(v);
                rs[i][r] += v;
            }
        }
    }
    int slot = (rest & 7) * 2 + (wave & 1);
#pragma unroll
    for (int i = 0; i < 4; ++i)
#pragma unroll
        for (int r = 0; r < 4; ++r) {
            float s = rs[i][r];
            s += __shfl_xor(s, 1);
            s += __shfl_xor(s, 2);
            s += __shfl_xor(s, 4);
            s += __shfl_xor(s, 8);
            if (l16 == 0)
                deg_part[((size_t)slot * BC + b) * NN + n0 + rowoff + i * 16 + quad * 4 + r] = s;
        }
}

// A := D A D in place (bf16); D = rsqrt(sum of 16 deg partials).
// 1D grid 16*BC: b = L&7, n0 = (L>>3)*64.
__global__ __launch_bounds__(256) void scaleA_kernel(
    ushort_t* __restrict__ Abf, const float* __restrict__ deg_part) {
    int L = blockIdx.x;
    int b = L & 7, n0 = (L >> 3) * 64;
    int t = threadIdx.x;
    __shared__ float dism[NN];
    for (int m = t; m < NN; m += 256) {
        float s = 0.f;
#pragma unroll
        for (int k = 0; k < 16; ++k) s += deg_part[((size_t)k * BC + b) * NN + m];
        dism[m] = rsqrtf(s);
    }
    __syncthreads();
    int c = t & 63;
#pragma unroll
    for (int rr = 0; rr < 16; ++rr) {
        int row = n0 + rr * 4 + (t >> 6);
        float dn = dism[row];
        ushort_t* Ar = Abf + ((size_t)b * NN + row) * NN;
#pragma unroll
        for (int o = 0; o < 2; ++o) {
            int oct = c + o * 64;
            uint4 v = *(const uint4*)(Ar + oct * 8);
            unsigned* w = (unsigned*)&v;
            ushort_t outp[8];
#pragma unroll
            for (int q = 0; q < 4; ++q) {
                int m = oct * 8 + q * 2;
                float a0 = bf2f((ushort_t)(w[q] & 0xffff));
                float a1 = bf2f((ushort_t)(w[q] >> 16));
                outp[2 * q]     = f2bf(dn * a0 * dism[m]);
                outp[2 * q + 1] = f2bf(dn * a1 * dism[m + 1]);
            }
            *(uint4*)(Ar + oct * 8) = *(uint4*)outp;
        }
    }
}

// lx: acc[f][n] = sum_k in_t[f][k] * Asc[n][k]  (Asc symmetric), dbuf K-loop.
// mode0: o = in_t - acc = X1; write X1t + X1b.  mode1: o = 2(in_t-acc)-x0t = X2b.
// 1D grid ft*8*BC: b = L&7; rest = L>>3; f_tile = rest%ft; n_tile = rest/ft.
__global__ __launch_bounds__(256) void lx_kernel(
    const ushort_t* __restrict__ Asc, const ushort_t* __restrict__ in_t,
    const ushort_t* __restrict__ x0t, ushort_t* __restrict__ out_t,
    ushort_t* __restrict__ out_b, int F, int Fp, int mode, int ft) {
    int t = threadIdx.x;
    int L = blockIdx.x;
    int b = L & 7;
    int rest = L >> 3;
    int m0 = (rest % ft) * 128;   // f tile
    int n0 = (rest / ft) * 128;   // n tile
    const ushort_t* Ain = in_t + (size_t)b * Fp * NN;
    const ushort_t* Ab = Asc + (size_t)b * NN * NN;

    int lane = t & 63, quad = lane >> 4, l16 = lane & 15, wave = t >> 6;
    int rowoff = (wave >> 1) * 64, coloff = (wave & 1) * 64;

    // dbuf: 2 stages x (As 5120 | Bs 5120) = 40 KB; epilogue reuses [0..16384)
    __shared__ __align__(16) ushort_t smem[20480];

    f32x4 acc[4][4];
#pragma unroll
    for (int i = 0; i < 4; ++i)
#pragma unroll
        for (int j = 0; j < 4; ++j) acc[i][j] = (f32x4){0.f, 0.f, 0.f, 0.f};

    int rr0 = t >> 2, kq = (t & 3) * 8;
    int rr1 = rr0 + 64;
    bool av0 = (m0 + rr0 < F), av1 = (m0 + rr1 < F);
    const ushort_t* pA0 = Ain + (size_t)(m0 + rr0) * NN + kq;
    const ushort_t* pA1 = Ain + (size_t)(m0 + rr1) * NN + kq;
    const ushort_t* pB0 = Ab + (size_t)(n0 + rr0) * NN + kq;
    const ushort_t* pB1 = Ab + (size_t)(n0 + rr1) * NN + kq;
    int o0 = rr0 * 40 + kq, o1 = rr1 * 40 + kq;
    const uint4 z4 = make_uint4(0u, 0u, 0u, 0u);

    {
        *(uint4*)&smem[o0]        = av0 ? *(const uint4*)pA0 : z4;
        *(uint4*)&smem[o1]        = av1 ? *(const uint4*)pA1 : z4;
        *(uint4*)&smem[5120 + o0] = *(const uint4*)pB0;
        *(uint4*)&smem[5120 + o1] = *(const uint4*)pB1;
    }
    __syncthreads();

    for (int it = 0; it < 32; ++it) {
        int cur = (it & 1) * 10240;
        int nxt = 10240 - cur;
        uint4 ra0, ra1, rb0, rb1;
        if (it < 31) {
            int k = (it + 1) * 32;
            ra0 = av0 ? *(const uint4*)(pA0 + k) : z4;
            ra1 = av1 ? *(const uint4*)(pA1 + k) : z4;
            rb0 = *(const uint4*)(pB0 + k);
            rb1 = *(const uint4*)(pB1 + k);
        }
        ushort_t* AsP = smem + cur;
        ushort_t* BsP = smem + cur + 5120;
        bf16x8 af[4], bfv[4];
#pragma unroll
        for (int i = 0; i < 4; ++i)
            af[i] = *(const bf16x8*)&AsP[(rowoff + i * 16 + l16) * 40 + quad * 8];
#pragma unroll
        for (int j = 0; j < 4; ++j)
            bfv[j] = *(const bf16x8*)&BsP[(coloff + j * 16 + l16) * 40 + quad * 8];
#pragma unroll
        for (int i = 0; i < 4; ++i)
#pragma unroll
            for (int j = 0; j < 4; ++j)
                acc[i][j] = __builtin_amdgcn_mfma_f32_16x16x32_bf16(af[i], bfv[j], acc[i][j], 0, 0, 0);
        if (it < 31) {
            *(uint4*)&smem[nxt + o0]        = ra0;
            *(uint4*)&smem[nxt + o1]        = ra1;
            *(uint4*)&smem[nxt + 5120 + o0] = rb0;
            *(uint4*)&smem[nxt + 5120 + o1] = rb1;
        }
        __syncthreads();
    }

#pragma unroll
    for (int j = 0; j < 4; ++j) {
        int nl = coloff + j * 16 + l16;
        int n = n0 + nl;
#pragma unroll
        for (int i = 0; i < 4; ++i) {
#pragma unroll
            for (int r = 0; r < 4; ++r) {
                int fl = rowoff + i * 16 + quad * 4 + r;
                int f = m0 + fl;
                float o = 0.f;
                if (f < F) {
                    float a = acc[i][j][r];
                    size_t off = (size_t)f * NN + n;
                    float xin = bf2f(Ain[off]);
                    if (mode == 0) {
                        o = xin - a;
                        out_t[(size_t)b * Fp * NN + off] = f2bf(o);
                    } else {
                        float x0 = bf2f(x0t[(size_t)b * Fp * NN + off]);
                        o = 2.f * (xin - a) - x0;
                    }
                }
                smem[nl * 128 + (((fl >> 3) ^ (nl & 7)) << 3) + (fl & 7)] = f2bf(o);
            }
        }
    }
    __syncthreads();
    for (int s2 = t; s2 < 2048; s2 += 256) {
        int nl = s2 >> 4, oct = s2 & 15;
        int fg = m0 + oct * 8;
        if (fg < Fp) {
            uint4 v = *(const uint4*)&smem[nl * 128 + ((oct ^ (nl & 7)) << 3)];
            *(uint4*)(out_b + ((size_t)b * NN + n0 + nl) * Fp + fg) = v;
        }
    }
}

// Out[r][g] = relu( sum_p Xp[r][:].Wt[p][g][:] + bias[g] ), dbuf over (p,k);
// layer3: fused maxpool. 1D grid n_g*64: c=L&7; rest=L>>3; g=rest%n_g;
// r_tile = c*8 + rest/n_g.
__global__ __launch_bounds__(256) void proj_kernel(
    const ushort_t* __restrict__ X0, const ushort_t* __restrict__ X1,
    const ushort_t* __restrict__ X2, const ushort_t* __restrict__ Wt,
    const float* __restrict__ bias, float* __restrict__ O, float* __restrict__ pool,
    int Fp, int Fo, int b0, int n_g) {
    int t = threadIdx.x;
    int L = blockIdx.x;
    int c = L & 7;
    int rest = L >> 3;
    int g0 = (rest % n_g) * 128;
    int r0 = (c * 8 + rest / n_g) * 128;
    int lane = t & 63, quad = lane >> 4, l16 = lane & 15, wave = t >> 6;
    int rowoff = (wave >> 1) * 64, coloff = (wave & 1) * 64;

    __shared__ __align__(16) ushort_t smem[20480];
    f32x4 acc[4][4];
#pragma unroll
    for (int i = 0; i < 4; ++i)
#pragma unroll
        for (int j = 0; j < 4; ++j) acc[i][j] = (f32x4){0.f, 0.f, 0.f, 0.f};

    const ushort_t* Xs[3] = {X0, X1, X2};
    int rr0 = t >> 2, kq = (t & 3) * 8;
    int rr1 = rr0 + 64;
    int o0 = rr0 * 40 + kq, o1 = rr1 * 40 + kq;
    int nk = Fp >> 5;
    int NIT = 3 * nk;

    {
        *(uint4*)&smem[o0]        = *(const uint4*)(X0 + (size_t)(r0 + rr0) * Fp + kq);
        *(uint4*)&smem[o1]        = *(const uint4*)(X0 + (size_t)(r0 + rr1) * Fp + kq);
        *(uint4*)&smem[5120 + o0] = *(const uint4*)(Wt + (size_t)(g0 + rr0) * Fp + kq);
        *(uint4*)&smem[5120 + o1] = *(const uint4*)(Wt + (size_t)(g0 + rr1) * Fp + kq);
    }
    __syncthreads();

    for (int it = 0; it < NIT; ++it) {
        int cur = (it & 1) * 10240;
        int nxt = 10240 - cur;
        uint4 ra0, ra1, rb0, rb1;
        if (it + 1 < NIT) {
            int idx = it + 1;
            int p = idx / nk;
            int k = (idx - p * nk) * 32 + kq;
            const ushort_t* Xp = Xs[p];
            const ushort_t* Wp = Wt + (size_t)p * Fo * Fp;
            ra0 = *(const uint4*)(Xp + (size_t)(r0 + rr0) * Fp + k);
            ra1 = *(const uint4*)(Xp + (size_t)(r0 + rr1) * Fp + k);
            rb0 = *(const uint4*)(Wp + (size_t)(g0 + rr0) * Fp + k);
            rb1 = *(const uint4*)(Wp + (size_t)(g0 + rr1) * Fp + k);
        }
        ushort_t* AsP = smem + cur;
        ushort_t* BsP = smem + cur + 5120;
        bf16x8 af[4], bfv[4];
#pragma unroll
        for (int i = 0; i < 4; ++i)
            af[i] = *(const bf16x8*)&AsP[(rowoff + i * 16 + l16) * 40 + quad * 8];
#pragma unroll
        for (int j = 0; j < 4; ++j)
            bfv[j] = *(const bf16x8*)&BsP[(coloff + j * 16 + l16) * 40 + quad * 8];
#pragma unroll
        for (int i = 0; i < 4; ++i)
#pragma unroll
            for (int j = 0; j < 4; ++j)
                acc[i][j] = __builtin_amdgcn_mfma_f32_16x16x32_bf16(af[i], bfv[j], acc[i][j], 0, 0, 0);
        if (it + 1 < NIT) {
            *(uint4*)&smem[nxt + o0]        = ra0;
            *(uint4*)&smem[nxt + o1]        = ra1;
            *(uint4*)&smem[nxt + 5120 + o0] = rb0;
            *(uint4*)&smem[nxt + 5120 + o1] = rb1;
        }
        __syncthreads();
    }

    float bias_l[4];
#pragma unroll
    for (int j = 0; j < 4; ++j) bias_l[j] = bias[g0 + coloff + j * 16 + l16];

    if (O) {
#pragma unroll
        for (int i = 0; i < 4; ++i) {
#pragma unroll
            for (int r = 0; r < 4; ++r) {
                int row = r0 + rowoff + i * 16 + quad * 4 + r;
#pragma unroll
                for (int j = 0; j < 4; ++j) {
                    int g = g0 + coloff + j * 16 + l16;
                    O[(size_t)row * Fo + g] = fmaxf(acc[i][j][r] + bias_l[j], 0.f);
                }
            }
        }
    } else {
        float mj[4];
#pragma unroll
        for (int j = 0; j < 4; ++j) {
            float m = 0.f;
#pragma unroll
            for (int i = 0; i < 4; ++i)
#pragma unroll
                for (int r = 0; r < 4; ++r)
                    m = fmaxf(m, acc[i][j][r] + bias_l[j]);
            m = fmaxf(m, 0.f);
            m = fmaxf(m, __shfl_xor(m, 16));
            m = fmaxf(m, __shfl_xor(m, 32));
            mj[j] = m;
        }
        if (quad == 0) {
            int smp = b0 + (r0 >> 10);
#pragma unroll
            for (int j = 0; j < 4; ++j)
                atomicMax((int*)&pool[(size_t)smp * 1024 + g0 + coloff + j * 16 + l16],
                          __float_as_int(mj[j]));
        }
    }
}

// fc: block = (row, 64-col tile); 4 K-slices x 64 cols; LDS reduce.
__global__ __launch_bounds__(256) void fc_kernel(
    const float* __restrict__ In, const float* __restrict__ W,
    const float* __restrict__ bias, float* __restrict__ out,
    int K, int Nout, int relu) {
    int r = blockIdx.y;
    int c0 = blockIdx.x * 64;
    int t = threadIdx.x;
    int cl = t & 63, ks = t >> 6;
    int c = c0 + cl;
    int kchunk = K >> 2;
    int k0 = ks * kchunk, k1 = k0 + kchunk;
    float s = 0.f;
    if (c < Nout) {
        const float* ip = In + (size_t)r * K;
        const float* wp = W + c;
#pragma unroll 4
        for (int k = k0; k < k1; ++k) s += ip[k] * wp[(size_t)k * Nout];
    }
    __shared__ float red[4][64];
    red[ks][cl] = s;
    __syncthreads();
    if (t < 64 && c0 + t < Nout) {
        float v = red[0][t] + red[1][t] + red[2][t] + red[3][t] + bias[c0 + t];
        if (relu) v = fmaxf(v, 0.f);
        out[(size_t)r * Nout + c0 + t] = v;
    }
}

// ---------------------------------------------------------------------------
extern "C" void kernel_launch(void* const* d_in, const int* in_sizes, int n_in,
                              void* d_out, int out_size, void* d_ws, size_t ws_size,
                              hipStream_t stream) {
    const float* x    = (const float*)d_in[0];
    const float* W1   = (const float*)d_in[1];
    const float* b1   = (const float*)d_in[2];
    const float* W2   = (const float*)d_in[3];
    const float* b2   = (const float*)d_in[4];
    const float* W3   = (const float*)d_in[5];
    const float* b3   = (const float*)d_in[6];
    const float* fc1w = (const float*)d_in[7];
    const float* fc1b = (const float*)d_in[8];
    const float* fc2w = (const float*)d_in[9];
    const float* fc2b = (const float*)d_in[10];
    const float* fc3w = (const float*)d_in[11];
    const float* fc3b = (const float*)d_in[12];
    float* out = (float*)d_out;

    const size_t SL = 4194304;                 // BC*NN*512 ushorts (max slab)
    ushort_t* Abf  = (ushort_t*)d_ws;          // 8M ushorts (16 MiB)
    ushort_t* X0hi = Abf + (size_t)8 * 1024 * 1024;
    ushort_t* X0lo = X0hi + SL;                // aliases X2b (disjoint lifetime)
    ushort_t* X0t  = X0lo + SL;
    ushort_t* X1t  = X0t + SL;
    ushort_t* X1b  = X1t + SL;
    ushort_t* Wt   = X1b + SL;                 // 1781760 ushorts
    float* O1   = (float*)(Wt + 1781760);      // 8192*128
    float* O2   = O1 + 1048576;                // 8192*512
    float* sq   = O2 + 4194304;                // 8192
    float* degp = sq + 8192;                   // 16*BC*NN = 131072
    float* pool = degp + 131072;               // 32*1024
    float* f1   = pool + 32768;                // 32*512
    float* f2   = f1 + 16384;                  // 32*128
    ushort_t* X2b = X0lo;                      // alias

    wconvT_kernel<<<dim3(2, 1, 3), 256, 0, stream>>>(W1, Wt, 6, 128, 32);
    wconvT_kernel<<<dim3(8, 2, 3), 256, 0, stream>>>(W2, Wt + 12288, 128, 512, 128);
    wconvT_kernel<<<dim3(16, 8, 3), 256, 0, stream>>>(W3, Wt + 208896, 512, 1024, 512);
    zero_kernel<<<128, 256, 0, stream>>>(pool, 32768);

    for (int c = 0; c < NCHUNK; ++c) {
        int b0 = c * BC;
        struct LayerDef {
            const float* X; int F, Fp, Fo;
            const ushort_t* Wtl; const float* bias; float* O;
        };
        LayerDef L[3] = {
            { x + (size_t)b0 * NN * 6, 6,   32,  128,  Wt,          b1, O1 },
            { O1,                      128, 128, 512,  Wt + 12288,  b2, O2 },
            { O2,                      512, 512, 1024, Wt + 208896, b3, nullptr },
        };
        for (int li = 0; li < 3; ++li) {
            LayerDef& Ld = L[li];
            int F = Ld.F, Fp = Ld.Fp;
            int ft = (F + 127) / 128;
            int n_g = Ld.Fo / 128;
            prep2_kernel<<<16 * BC, 256, 0, stream>>>(Ld.X, X0hi, X0lo, X0t, sq, F, Fp);
            adj_kernel<<<64 * BC, 256, 0, stream>>>(X0hi, X0lo, sq, Abf, degp, Fp);
            scaleA_kernel<<<16 * BC, 256, 0, stream>>>(Abf, degp);
            lx_kernel<<<ft * 8 * BC, 256, 0, stream>>>(
                Abf, X0t, nullptr, X1t, X1b, F, Fp, 0, ft);
            lx_kernel<<<ft * 8 * BC, 256, 0, stream>>>(
                Abf, X1t, X0t, nullptr, X2b, F, Fp, 1, ft);
            proj_kernel<<<n_g * 64, 256, 0, stream>>>(
                X0hi, X1b, X2b, Ld.Wtl, Ld.bias, Ld.O, pool, Fp, Ld.Fo, b0, n_g);
        }
    }

    fc_kernel<<<dim3(8, 32), 256, 0, stream>>>(pool, fc1w, fc1b, f1, 1024, 512, 1);
    fc_kernel<<<dim3(2, 32), 256, 0, stream>>>(f1, fc2w, fc2b, f2, 512, 128, 1);
    fc_kernel<<<dim3(1, 32), 256, 0, stream>>>(f2, fc3w, fc3b, out, 128, 40, 0);
}